// Round 1
// baseline (834.624 us; speedup 1.0000x reference)
//
#include <hip/hip_runtime.h>

typedef unsigned int u32;
typedef unsigned short u16;
typedef unsigned long long u64;

#define HMAX 1024   // max heavy (deg>S) nodes tracked; expected ~65, 1024 = huge margin
#define MAXD 128    // max out-degree bucketed; expected max ~58

// ---------------- threefry2x32 (exact JAX cipher) ----------------
__host__ __device__ inline void tf2x32(u32 k0, u32 k1, u32 x0, u32 x1, u32& o0, u32& o1) {
  u32 ks2 = k0 ^ k1 ^ 0x1BD11BDAu;
#define ROTL32(x,d) (((x)<<(d))|((x)>>(32-(d))))
#define TFR(r) { x0 += x1; x1 = ROTL32(x1,(r)); x1 ^= x0; }
  x0 += k0; x1 += k1;
  TFR(13) TFR(15) TFR(26) TFR(6)
  x0 += k1; x1 += ks2 + 1u;
  TFR(17) TFR(29) TFR(16) TFR(24)
  x0 += ks2; x1 += k0 + 2u;
  TFR(13) TFR(15) TFR(26) TFR(6)
  x0 += k0; x1 += k1 + 3u;
  TFR(17) TFR(29) TFR(16) TFR(24)
  x0 += k1; x1 += ks2 + 4u;
  TFR(13) TFR(15) TFR(26) TFR(6)
  x0 += ks2; x1 += k0 + 5u;
  o0 = x0; o1 = x1;
#undef TFR
#undef ROTL32
}

__device__ inline float bf2f(u16 b) { return __uint_as_float(((u32)b) << 16); }
__device__ inline u16 f2bf(float f) {      // round-to-nearest-even (finite inputs)
  u32 u = __float_as_uint(f);
  return (u16)((u + 0x7FFFu + ((u >> 16) & 1u)) >> 16);
}

// ---------------- graph setup kernels ----------------
__global__ __launch_bounds__(256) void k_deg0(const int* __restrict__ ei, int* __restrict__ outdeg,
                                              int* __restrict__ indeg, int E) {
  int e = blockIdx.x * 256 + threadIdx.x;
  if (e >= E) return;
  atomicAdd(&outdeg[ei[e]], 1);
  atomicAdd(&indeg[ei[E + e]], 1);
}

__global__ __launch_bounds__(256) void k_heavy(const int* __restrict__ outdeg, int* __restrict__ heavy_idx,
                                               int* __restrict__ hcount, int N, int S) {
  int v = blockIdx.x * 256 + threadIdx.x;
  if (v >= N) return;
  if (outdeg[v] > S) {
    int id = atomicAdd(hcount, 1);
    if (id < HMAX) heavy_idx[v] = id;
  }
}

// bucket edges of heavy src nodes with key (bits>>9, edge_id) packed into u64
__global__ __launch_bounds__(256) void k_bfill(const int* __restrict__ ei, const int* __restrict__ heavy_idx,
                                               int* __restrict__ bcount, u64* __restrict__ bucket,
                                               int E, u32 ka, u32 kb) {
  int e = blockIdx.x * 256 + threadIdx.x;
  if (e >= E) return;
  int hi = heavy_idx[ei[e]];
  if (hi < 0 || hi >= HMAX) return;
  u32 w0, w1;
  tf2x32(ka, kb, 0u, (u32)e, w0, w1);       // partitionable: counts = (hi32,lo32) of 64-bit iota
  u32 r = (w0 ^ w1) >> 9;                    // uniform-float compare == 23-bit compare
  int slot = atomicAdd(&bcount[hi], 1);
  if (slot < MAXD) bucket[(size_t)hi * MAXD + slot] = ((u64)r << 32) | (u32)e;
}

// rank each bucketed edge by (key, idx); drop rank >= S  (clears `bit` in mask)
__global__ __launch_bounds__(256) void k_rank(const int* __restrict__ hcount, const int* __restrict__ bcount,
                                              const u64* __restrict__ bucket, unsigned char* __restrict__ mask,
                                              int S, int bit) {
  int wid = (blockIdx.x * 256 + threadIdx.x) >> 6;
  int lane = threadIdx.x & 63;
  int hc = hcount[0]; if (hc > HMAX) hc = HMAX;
  if (wid >= hc) return;
  int d = bcount[wid]; if (d > MAXD) d = MAXD;
  const u64* B = bucket + (size_t)wid * MAXD;
  for (int i = lane; i < d; i += 64) {
    u64 ki = B[i];
    int rank = 0;
    for (int j = 0; j < d; ++j) rank += (B[j] < ki) ? 1 : 0;
    if (rank >= S) {
      u32 e = (u32)ki;
      mask[e] = (unsigned char)(mask[e] & ~bit);   // byte store, one writer per e per phase
    }
  }
}

__global__ __launch_bounds__(256) void k_degm(const int* __restrict__ ei, const unsigned char* __restrict__ mask,
                                              int* __restrict__ deg1, int* __restrict__ deg2, int E) {
  int e = blockIdx.x * 256 + threadIdx.x;
  if (e >= E) return;
  unsigned char m = mask[e];
  int d = ei[E + e];
  if (m & 1) atomicAdd(&deg1[d], 1);
  if (m & 2) atomicAdd(&deg2[d], 1);
}

__global__ __launch_bounds__(256) void k_dinv(const int* __restrict__ deg1, const int* __restrict__ deg2,
                                              float* __restrict__ dinv1, float* __restrict__ dinv2, int N) {
  int v = blockIdx.x * 256 + threadIdx.x;
  if (v >= N) return;
  dinv1[v] = 1.0f / sqrtf((float)(deg1[v] + 1));   // +1 self loop; deg>=1 always
  dinv2[v] = 1.0f / sqrtf((float)(deg2[v] + 1));
}

// ---------------- 3-kernel exclusive scan (indeg -> dst_ptr) ----------------
__global__ __launch_bounds__(256) void k_scan_a(const int* __restrict__ in, int* __restrict__ outExcl,
                                                int* __restrict__ partial, int N) {
  int b = blockIdx.x, t = threadIdx.x, i = b * 256 + t;
  int v = (i < N) ? in[i] : 0;
  int lane = t & 63, w = t >> 6;
  int incl = v;
  for (int off = 1; off < 64; off <<= 1) { int nb = __shfl_up(incl, off, 64); if (lane >= off) incl += nb; }
  __shared__ int ws4[4]; __shared__ int tot;
  if (lane == 63) ws4[w] = incl;
  __syncthreads();
  if (t == 0) { int s = 0; for (int k = 0; k < 4; ++k) { int xk = ws4[k]; ws4[k] = s; s += xk; } tot = s; }
  __syncthreads();
  int excl = incl - v + ws4[w];
  if (i < N) outExcl[i] = excl;
  if (t == 0) partial[b] = tot;
}

__global__ __launch_bounds__(256) void k_scan_b(int* __restrict__ partial, int* __restrict__ ptr, int nb, int N) {
  int t = threadIdx.x;
  int v = (t < nb) ? partial[t] : 0;
  int lane = t & 63, w = t >> 6;
  int incl = v;
  for (int off = 1; off < 64; off <<= 1) { int nbr = __shfl_up(incl, off, 64); if (lane >= off) incl += nbr; }
  __shared__ int ws4[4]; __shared__ int tot;
  if (lane == 63) ws4[w] = incl;
  __syncthreads();
  if (t == 0) { int s = 0; for (int k = 0; k < 4; ++k) { int xk = ws4[k]; ws4[k] = s; s += xk; } tot = s; }
  __syncthreads();
  int excl = incl - v + ws4[w];
  if (t < nb) partial[t] = excl;
  if (t == 0) ptr[N] = tot;
}

__global__ __launch_bounds__(256) void k_scan_c(int* __restrict__ ptr, int* __restrict__ cursor,
                                                const int* __restrict__ partial, int N) {
  int i = blockIdx.x * 256 + threadIdx.x;
  if (i >= N) return;
  int val = ptr[i] + partial[blockIdx.x];
  ptr[i] = val; cursor[i] = val;
}

__global__ __launch_bounds__(256) void k_scatter(const int* __restrict__ ei, const unsigned char* __restrict__ mask,
                                                 int* __restrict__ cursor, u32* __restrict__ entries, int E) {
  int e = blockIdx.x * 256 + threadIdx.x;
  if (e >= E) return;
  int s = ei[e], d = ei[E + e];
  unsigned char m = mask[e];
  int pos = atomicAdd(&cursor[d], 1);
  entries[pos] = (u32)s | ((m & 1) ? (1u << 30) : 0u) | ((m & 2) ? (1u << 31) : 0u);
}

// ---------------- GEMMs (vector fp32, small) ----------------
__global__ __launch_bounds__(256) void k_gemm1(const float* __restrict__ x, const float* __restrict__ W1,
                                               u16* __restrict__ h1b, int N) {
  __shared__ float xs[16 * 256];
  int row0 = blockIdx.x * 16;
  int t = threadIdx.x;
  int nrows = min(16, N - row0);
  for (int i = t; i < nrows * 64; i += 256)
    ((float4*)xs)[i] = ((const float4*)(x + (size_t)row0 * 256))[i];
  __syncthreads();
  int c = t & 63, rs = t >> 6;
  float acc[4] = {0.f, 0.f, 0.f, 0.f};
  for (int k = 0; k < 256; ++k) {
    float w = W1[k * 64 + c];
#pragma unroll
    for (int i2 = 0; i2 < 4; ++i2) acc[i2] = fmaf(xs[(rs * 4 + i2) * 256 + k], w, acc[i2]);
  }
#pragma unroll
  for (int i2 = 0; i2 < 4; ++i2) {
    int r = row0 + rs * 4 + i2;
    if (r < N) h1b[(size_t)r * 64 + c] = f2bf(acc[i2]);
  }
}

__global__ __launch_bounds__(256) void k_gemm2(const float* __restrict__ hn, const float* __restrict__ W2,
                                               u16* __restrict__ h2b, int N) {
  __shared__ float xs[8 * 64];
  int row0 = blockIdx.x * 8;
  int t = threadIdx.x;
  int nrows = min(8, N - row0);
  for (int i = t; i < nrows * 16; i += 256)
    ((float4*)xs)[i] = ((const float4*)(hn + (size_t)row0 * 64))[i];
  __syncthreads();
  int c = t & 127, rs = t >> 7;
  float acc[4] = {0.f, 0.f, 0.f, 0.f};
  for (int k = 0; k < 64; ++k) {
    float w = W2[k * 128 + c];
#pragma unroll
    for (int i2 = 0; i2 < 4; ++i2) acc[i2] = fmaf(xs[(rs * 4 + i2) * 64 + k], w, acc[i2]);
  }
#pragma unroll
  for (int i2 = 0; i2 < 4; ++i2) {
    int r = row0 + rs * 4 + i2;
    if (r < N) h2b[(size_t)r * 128 + c] = f2bf(acc[i2]);
  }
}

// ---------------- conv1: aggregate + bias + relu + L2 normalize ----------------
__global__ __launch_bounds__(256) void k_conv1(const int* __restrict__ ptr, const u32* __restrict__ entries,
                                               const float* __restrict__ dinv1, const u16* __restrict__ h1b,
                                               const float* __restrict__ b1, float* __restrict__ hn, int N) {
  int wid = (blockIdx.x * 256 + threadIdx.x) >> 6;
  if (wid >= N) return;
  int lane = threadIdx.x & 63;
  int beg = ptr[wid], end = ptr[wid + 1];
  float acc = 0.f;
  for (int cb = beg; cb < end; cb += 64) {
    int nv = min(64, end - cb);
    float wgt = 0.f; int entL = 0;
    if (lane < nv) {
      u32 e = entries[cb + lane]; entL = (int)e;
      if (e & (1u << 30)) wgt = dinv1[e & 0x3FFFFFFFu];   // dinv>0 always => wgt==0 <=> masked
    }
    for (int i = 0; i < nv; ++i) {
      float w = __shfl(wgt, i, 64);
      if (w != 0.f) {
        int s = __shfl(entL, i, 64) & 0x3FFFFFFF;
        acc = fmaf(w, bf2f(h1b[(size_t)s * 64 + lane]), acc);
      }
    }
  }
  float dv = dinv1[wid];
  acc = fmaf(dv, bf2f(h1b[(size_t)wid * 64 + lane]), acc);  // self loop
  float o = fmaf(dv, acc, b1[lane]);
  o = fmaxf(o, 0.f);
  float ss = o * o;
#pragma unroll
  for (int off = 32; off > 0; off >>= 1) ss += __shfl_xor(ss, off, 64);
  float scale = 1.f / fmaxf(sqrtf(ss), 1e-12f);
  hn[(size_t)wid * 64 + lane] = o * scale;
}

// ---------------- conv2: aggregate + bias -> out ----------------
__global__ __launch_bounds__(256) void k_conv2(const int* __restrict__ ptr, const u32* __restrict__ entries,
                                               const float* __restrict__ dinv2, const u32* __restrict__ h2u,
                                               const float* __restrict__ b2, float* __restrict__ out, int N) {
  int wid = (blockIdx.x * 256 + threadIdx.x) >> 6;
  if (wid >= N) return;
  int lane = threadIdx.x & 63;
  int beg = ptr[wid], end = ptr[wid + 1];
  float a0 = 0.f, a1 = 0.f;
  for (int cb = beg; cb < end; cb += 64) {
    int nv = min(64, end - cb);
    float wgt = 0.f; int entL = 0;
    if (lane < nv) {
      u32 e = entries[cb + lane]; entL = (int)e;
      if (e & (1u << 31)) wgt = dinv2[e & 0x3FFFFFFFu];
    }
    for (int i = 0; i < nv; ++i) {
      float w = __shfl(wgt, i, 64);
      if (w != 0.f) {
        u32 s = (u32)__shfl(entL, i, 64) & 0x3FFFFFFFu;
        u32 u = h2u[(size_t)s * 64 + lane];
        a0 = fmaf(w, __uint_as_float(u << 16), a0);
        a1 = fmaf(w, __uint_as_float(u & 0xFFFF0000u), a1);
      }
    }
  }
  float dv = dinv2[wid];
  u32 u = h2u[(size_t)wid * 64 + lane];
  a0 = fmaf(dv, __uint_as_float(u << 16), a0);
  a1 = fmaf(dv, __uint_as_float(u & 0xFFFF0000u), a1);
  float2 bb = ((const float2*)b2)[lane];
  float2 res; res.x = fmaf(dv, a0, bb.x); res.y = fmaf(dv, a1, bb.y);
  ((float2*)out)[(size_t)wid * 64 + lane] = res;
}

// ---------------- launch ----------------
extern "C" void kernel_launch(void* const* d_in, const int* in_sizes, int n_in,
                              void* d_out, int out_size, void* d_ws, size_t ws_size,
                              hipStream_t stream) {
  const float* x  = (const float*)d_in[0];
  const int*   ei = (const int*)d_in[1];     // [2*E] int32 (harness converts ints to int32)
  const float* W1 = (const float*)d_in[2];
  const float* b1 = (const float*)d_in[3];
  const float* W2 = (const float*)d_in[4];
  const float* b2 = (const float*)d_in[5];
  const int N = in_sizes[0] / 256;
  const int E = in_sizes[1] / 2;

  // JAX: key(42) -> split -> sk1, sk2 (partitionable/foldlike: enc(key,(0,0)), enc(key,(0,1)))
  u32 sk1a, sk1b, sk2a, sk2b;
  tf2x32(0u, 42u, 0u, 0u, sk1a, sk1b);
  tf2x32(0u, 42u, 0u, 1u, sk2a, sk2b);

  // workspace layout (256B aligned slabs)
  char* p = (char*)d_ws;
  auto alloc = [&](size_t bytes) { char* r = p; p += (bytes + 255) & ~(size_t)255; return r; };
  u16* h1b      = (u16*)alloc((size_t)N * 64 * 2);
  float* hn     = (float*)alloc((size_t)N * 64 * 4);
  u16* h2b      = (u16*)alloc((size_t)N * 128 * 2);
  int* outdeg   = (int*)alloc((size_t)N * 4);
  int* indeg    = (int*)alloc((size_t)N * 4);
  int* deg1     = (int*)alloc((size_t)N * 4);
  int* deg2     = (int*)alloc((size_t)N * 4);
  float* dinv1  = (float*)alloc((size_t)N * 4);
  float* dinv2  = (float*)alloc((size_t)N * 4);
  int* dptr     = (int*)alloc((size_t)(N + 1) * 4);
  int* cursor   = (int*)alloc((size_t)N * 4);
  u32* entries  = (u32*)alloc((size_t)E * 4);
  unsigned char* mask = (unsigned char*)alloc((size_t)E);
  int* heavy_idx = (int*)alloc((size_t)N * 4);
  int* hcb      = (int*)alloc((size_t)(1 + HMAX) * 4);   // [hcount | bcount[HMAX]]
  u64* bucket   = (u64*)alloc((size_t)HMAX * MAXD * 8);
  const int nbScan = (N + 255) / 256;
  int* partial  = (int*)alloc((size_t)nbScan * 4);

  int* hcount = hcb;
  int* bcount = hcb + 1;

  const int gE = (E + 255) / 256;
  const int gN = (N + 255) / 256;

  // init
  hipMemsetAsync(outdeg, 0, (size_t)N * 4, stream);
  hipMemsetAsync(indeg,  0, (size_t)N * 4, stream);
  hipMemsetAsync(deg1,   0, (size_t)N * 4, stream);
  hipMemsetAsync(deg2,   0, (size_t)N * 4, stream);
  hipMemsetAsync(mask, 0x03, (size_t)E, stream);         // both masks default keep

  k_deg0<<<gE, 256, 0, stream>>>(ei, outdeg, indeg, E);

  // phase A: m1 (S=100, key sk1) — statistically keeps everything, computed anyway
  hipMemsetAsync(heavy_idx, 0xFF, (size_t)N * 4, stream);
  hipMemsetAsync(hcb, 0, (size_t)(1 + HMAX) * 4, stream);
  k_heavy<<<gN, 256, 0, stream>>>(outdeg, heavy_idx, hcount, N, 100);
  k_bfill<<<gE, 256, 0, stream>>>(ei, heavy_idx, bcount, bucket, E, sk1a, sk1b);
  k_rank<<<HMAX / 4, 256, 0, stream>>>(hcount, bcount, bucket, mask, 100, 0x1);

  // phase B: m2 (S=50, key sk2)
  hipMemsetAsync(heavy_idx, 0xFF, (size_t)N * 4, stream);
  hipMemsetAsync(hcb, 0, (size_t)(1 + HMAX) * 4, stream);
  k_heavy<<<gN, 256, 0, stream>>>(outdeg, heavy_idx, hcount, N, 50);
  k_bfill<<<gE, 256, 0, stream>>>(ei, heavy_idx, bcount, bucket, E, sk2a, sk2b);
  k_rank<<<HMAX / 4, 256, 0, stream>>>(hcount, bcount, bucket, mask, 50, 0x2);

  // degrees with masks -> dinv
  k_degm<<<gE, 256, 0, stream>>>(ei, mask, deg1, deg2, E);
  k_dinv<<<gN, 256, 0, stream>>>(deg1, deg2, dinv1, dinv2, N);

  // dst-CSR
  k_scan_a<<<nbScan, 256, 0, stream>>>(indeg, dptr, partial, N);
  k_scan_b<<<1, 256, 0, stream>>>(partial, dptr, nbScan, N);
  k_scan_c<<<nbScan, 256, 0, stream>>>(dptr, cursor, partial, N);
  k_scatter<<<gE, 256, 0, stream>>>(ei, mask, cursor, entries, E);

  // compute pipeline
  k_gemm1<<<(N + 15) / 16, 256, 0, stream>>>(x, W1, h1b, N);
  k_conv1<<<(N * 64 + 255) / 256, 256, 0, stream>>>(dptr, entries, dinv1, h1b, b1, hn, N);
  k_gemm2<<<(N + 7) / 8, 256, 0, stream>>>(hn, W2, h2b, N);
  k_conv2<<<(N * 64 + 255) / 256, 256, 0, stream>>>(dptr, entries, dinv2, (const u32*)h2b, b2,
                                                    (float*)d_out, N);
}

// Round 2
// 579.485 us; speedup vs baseline: 1.4403x; 1.4403x over previous
//
#include <hip/hip_runtime.h>

typedef unsigned int u32;
typedef unsigned short u16;
typedef unsigned long long u64;

#define HMAX 1024   // max heavy (deg>S) nodes tracked; expected ~65
#define MAXD 128    // max out-degree bucketed; expected max ~58
// dst buckets: 512 nodes each; N=50000 -> 98 buckets (must be <=128)

// ---------------- threefry2x32 (exact JAX cipher) ----------------
__host__ __device__ inline void tf2x32(u32 k0, u32 k1, u32 x0, u32 x1, u32& o0, u32& o1) {
  u32 ks2 = k0 ^ k1 ^ 0x1BD11BDAu;
#define ROTL32(x,d) (((x)<<(d))|((x)>>(32-(d))))
#define TFR(r) { x0 += x1; x1 = ROTL32(x1,(r)); x1 ^= x0; }
  x0 += k0; x1 += k1;
  TFR(13) TFR(15) TFR(26) TFR(6)
  x0 += k1; x1 += ks2 + 1u;
  TFR(17) TFR(29) TFR(16) TFR(24)
  x0 += ks2; x1 += k0 + 2u;
  TFR(13) TFR(15) TFR(26) TFR(6)
  x0 += k0; x1 += k1 + 3u;
  TFR(17) TFR(29) TFR(16) TFR(24)
  x0 += k1; x1 += ks2 + 4u;
  TFR(13) TFR(15) TFR(26) TFR(6)
  x0 += ks2; x1 += k0 + 5u;
  o0 = x0; o1 = x1;
#undef TFR
#undef ROTL32
}

__device__ inline float bf2f(u16 b) { return __uint_as_float(((u32)b) << 16); }
__device__ inline u16 f2bf(float f) {      // round-to-nearest-even (finite inputs)
  u32 u = __float_as_uint(f);
  return (u16)((u + 0x7FFFu + ((u >> 16) & 1u)) >> 16);
}

// ---------------- phase 0: outdeg + dst-bucket histogram ----------------
#define H0CHUNK 4096
__global__ __launch_bounds__(256) void k_hist0(const int* __restrict__ ei, int* __restrict__ outdeg,
                                               int* __restrict__ bucketCount, int E, int nb) {
  __shared__ u32 hist[128];
  int t = threadIdx.x;
  if (t < 128) hist[t] = 0;
  __syncthreads();
  int lo = blockIdx.x * H0CHUNK;
  int hi = min(lo + H0CHUNK, E);
  for (int i = lo + t; i < hi; i += 256) {
    int s = ei[i];
    int d = ei[E + i];
    atomicAdd(&outdeg[s], 1);
    atomicAdd(&hist[d >> 9], 1u);
  }
  __syncthreads();
  if (t < nb && hist[t]) atomicAdd(&bucketCount[t], (int)hist[t]);
}

// ---------------- tiny scan: bucketCount -> bucketBase / bucketCur ----------------
__global__ void k_scanbk(const int* __restrict__ bucketCount, int* __restrict__ bucketBase,
                         int* __restrict__ bucketCur, int* __restrict__ dptr, int nb, int N) {
  if (threadIdx.x == 0) {
    int s = 0;
    for (int i = 0; i < nb; ++i) { bucketBase[i] = s; bucketCur[i] = s; s += bucketCount[i]; }
    bucketBase[nb] = s;
    dptr[N] = s;   // == E
  }
}

// ---------------- heavy detection (both sample phases in one sweep) ----------------
__global__ __launch_bounds__(256) void k_heavy2(const int* __restrict__ outdeg,
                                                int* __restrict__ hA, int* __restrict__ hB,
                                                int* __restrict__ hcA, int* __restrict__ hcB, int N) {
  int v = blockIdx.x * 256 + threadIdx.x;
  if (v >= N) return;
  int d = outdeg[v];
  if (d > 100) { int id = atomicAdd(hcA, 1); if (id < HMAX) hA[v] = id; }
  if (d > 50)  { int id = atomicAdd(hcB, 1); if (id < HMAX) hB[v] = id; }
}

// ---------------- bucket heavy edges with PRNG keys (both phases, one sweep) ----------------
__global__ __launch_bounds__(256) void k_bfill2(const int* __restrict__ ei,
                                                const int* __restrict__ hA, const int* __restrict__ hB,
                                                int* __restrict__ bcA, u64* __restrict__ bukA,
                                                int* __restrict__ bcB, u64* __restrict__ bukB,
                                                int E, u32 kaA, u32 kbA, u32 kaB, u32 kbB) {
  int e = blockIdx.x * 256 + threadIdx.x;
  if (e >= E) return;
  int s = ei[e];
  int ia = hA[s], ib = hB[s];
  if (ia >= 0 && ia < HMAX) {
    u32 w0, w1; tf2x32(kaA, kbA, 0u, (u32)e, w0, w1);
    u32 r = (w0 ^ w1) >> 9;
    int slot = atomicAdd(&bcA[ia], 1);
    if (slot < MAXD) bukA[(size_t)ia * MAXD + slot] = ((u64)r << 32) | (u32)e;
  }
  if (ib >= 0 && ib < HMAX) {
    u32 w0, w1; tf2x32(kaB, kbB, 0u, (u32)e, w0, w1);
    u32 r = (w0 ^ w1) >> 9;
    int slot = atomicAdd(&bcB[ib], 1);
    if (slot < MAXD) bukB[(size_t)ib * MAXD + slot] = ((u64)r << 32) | (u32)e;
  }
}

// rank each bucketed edge by (key, idx); drop rank >= S  (clears `bit` in mask)
__global__ __launch_bounds__(256) void k_rank(const int* __restrict__ hcount, const int* __restrict__ bcount,
                                              const u64* __restrict__ bucket, unsigned char* __restrict__ mask,
                                              int S, int bit) {
  int wid = (blockIdx.x * 256 + threadIdx.x) >> 6;
  int lane = threadIdx.x & 63;
  int hc = hcount[0]; if (hc > HMAX) hc = HMAX;
  if (wid >= hc) return;
  int d = bcount[wid]; if (d > MAXD) d = MAXD;
  const u64* B = bucket + (size_t)wid * MAXD;
  for (int i = lane; i < d; i += 64) {
    u64 ki = B[i];
    int rank = 0;
    for (int j = 0; j < d; ++j) rank += (B[j] < ki) ? 1 : 0;
    if (rank >= S) {
      u32 e = (u32)ki;
      mask[e] = (unsigned char)(mask[e] & ~bit);   // byte store, one writer per e per phase
    }
  }
}

// ---------------- phase 1: binned scatter of edge records ----------------
// record = src(0:15) | dstlow(16:24) | m1(25) | m2(26)
#define P1CHUNK 8192
__global__ __launch_bounds__(256) void k_phase1(const int* __restrict__ ei,
                                                const unsigned char* __restrict__ mask,
                                                int* __restrict__ bucketCur, u32* __restrict__ records, int E) {
  __shared__ u32 lc[128];
  __shared__ u32 lbase[128];
  int t = threadIdx.x;
  if (t < 128) lc[t] = 0;
  __syncthreads();
  int lo = blockIdx.x * P1CHUNK;
  int hi = min(lo + P1CHUNK, E);
  for (int i = lo + t; i < hi; i += 256) {
    int d = ei[E + i];
    atomicAdd(&lc[d >> 9], 1u);
  }
  __syncthreads();
  if (t < 128) {
    u32 c = lc[t];
    if (c) lbase[t] = (u32)atomicAdd(&bucketCur[t], (int)c);
    lc[t] = 0;   // becomes local cursor
  }
  __syncthreads();
  for (int i = lo + t; i < hi; i += 256) {
    int s = ei[i];
    int d = ei[E + i];
    unsigned char m = mask[i];
    int bk = d >> 9;
    u32 slot = lbase[bk] + atomicAdd(&lc[bk], 1u);
    records[slot] = (u32)s | ((u32)(d & 511) << 16) | ((u32)(m & 3u) << 25);
  }
}

// ---------------- phase 2: per-bucket counting sort -> entries/dptr/dinv ----------------
__global__ __launch_bounds__(256) void k_phase2(const int* __restrict__ bucketBase,
                                                const u32* __restrict__ records,
                                                u32* __restrict__ entries, int* __restrict__ dptr,
                                                float* __restrict__ dinv1, float* __restrict__ dinv2, int N) {
  int b = blockIdx.x;
  int lo = bucketBase[b], hi = bucketBase[b + 1];
  __shared__ u32 cnt[512];
  __shared__ u32 ws4[4];
  int t = threadIdx.x;
  cnt[t] = 0; cnt[t + 256] = 0;
  __syncthreads();
  // packed histogram: total(0:9) | m1count(10:19) | m2count(20:29); max indeg ~70 << 1024
  for (int i = lo + t; i < hi; i += 256) {
    u32 r = records[i];
    u32 dl = (r >> 16) & 511u;
    u32 add = 1u + (((r >> 25) & 1u) << 10) + (((r >> 26) & 1u) << 20);
    atomicAdd(&cnt[dl], add);
  }
  __syncthreads();
  u32 c0 = cnt[2 * t], c1 = cnt[2 * t + 1];
  u32 n0 = c0 & 1023u, n1 = c1 & 1023u;
  u32 pair = n0 + n1;
  int lane = t & 63, w = t >> 6;
  u32 incl = pair;
  for (int off = 1; off < 64; off <<= 1) {
    u32 nbv = (u32)__shfl_up((int)incl, off, 64);
    if (lane >= off) incl += nbv;
  }
  if (lane == 63) ws4[w] = incl;
  __syncthreads();
  if (t == 0) { u32 s = 0; for (int k = 0; k < 4; ++k) { u32 x = ws4[k]; ws4[k] = s; s += x; } }
  __syncthreads();
  u32 excl = incl - pair + ws4[w];
  int v0 = b * 512 + 2 * t;
  if (v0 < N) {
    dptr[v0] = lo + (int)excl;
    dinv1[v0] = 1.0f / sqrtf((float)(((c0 >> 10) & 1023u) + 1u));
    dinv2[v0] = 1.0f / sqrtf((float)(((c0 >> 20) & 1023u) + 1u));
  }
  if (v0 + 1 < N) {
    dptr[v0 + 1] = lo + (int)(excl + n0);
    dinv1[v0 + 1] = 1.0f / sqrtf((float)(((c1 >> 10) & 1023u) + 1u));
    dinv2[v0 + 1] = 1.0f / sqrtf((float)(((c1 >> 20) & 1023u) + 1u));
  }
  __syncthreads();
  cnt[2 * t] = excl;            // cursors
  cnt[2 * t + 1] = excl + n0;
  __syncthreads();
  for (int i = lo + t; i < hi; i += 256) {
    u32 r = records[i];
    u32 dl = (r >> 16) & 511u;
    u32 slot = atomicAdd(&cnt[dl], 1u);
    entries[lo + slot] = (r & 0xFFFFu) | ((r & (1u << 25)) ? (1u << 30) : 0u)
                                       | ((r & (1u << 26)) ? (1u << 31) : 0u);
  }
}

// ---------------- GEMMs (vector fp32, small) ----------------
__global__ __launch_bounds__(256) void k_gemm1(const float* __restrict__ x, const float* __restrict__ W1,
                                               u16* __restrict__ h1b, int N) {
  __shared__ float xs[16 * 256];
  int row0 = blockIdx.x * 16;
  int t = threadIdx.x;
  int nrows = min(16, N - row0);
  for (int i = t; i < nrows * 64; i += 256)
    ((float4*)xs)[i] = ((const float4*)(x + (size_t)row0 * 256))[i];
  __syncthreads();
  int c = t & 63, rs = t >> 6;
  float acc[4] = {0.f, 0.f, 0.f, 0.f};
  for (int k = 0; k < 256; ++k) {
    float w = W1[k * 64 + c];
#pragma unroll
    for (int i2 = 0; i2 < 4; ++i2) acc[i2] = fmaf(xs[(rs * 4 + i2) * 256 + k], w, acc[i2]);
  }
#pragma unroll
  for (int i2 = 0; i2 < 4; ++i2) {
    int r = row0 + rs * 4 + i2;
    if (r < N) h1b[(size_t)r * 64 + c] = f2bf(acc[i2]);
  }
}

__global__ __launch_bounds__(256) void k_gemm2(const float* __restrict__ hn, const float* __restrict__ W2,
                                               u16* __restrict__ h2b, int N) {
  __shared__ float xs[8 * 64];
  int row0 = blockIdx.x * 8;
  int t = threadIdx.x;
  int nrows = min(8, N - row0);
  for (int i = t; i < nrows * 16; i += 256)
    ((float4*)xs)[i] = ((const float4*)(hn + (size_t)row0 * 64))[i];
  __syncthreads();
  int c = t & 127, rs = t >> 7;
  float acc[4] = {0.f, 0.f, 0.f, 0.f};
  for (int k = 0; k < 64; ++k) {
    float w = W2[k * 128 + c];
#pragma unroll
    for (int i2 = 0; i2 < 4; ++i2) acc[i2] = fmaf(xs[(rs * 4 + i2) * 64 + k], w, acc[i2]);
  }
#pragma unroll
  for (int i2 = 0; i2 < 4; ++i2) {
    int r = row0 + rs * 4 + i2;
    if (r < N) h2b[(size_t)r * 128 + c] = f2bf(acc[i2]);
  }
}

// ---------------- conv1: aggregate + bias + relu + L2 normalize ----------------
__global__ __launch_bounds__(256) void k_conv1(const int* __restrict__ ptr, const u32* __restrict__ entries,
                                               const float* __restrict__ dinv1, const u16* __restrict__ h1b,
                                               const float* __restrict__ b1, float* __restrict__ hn, int N) {
  int wid = (blockIdx.x * 256 + threadIdx.x) >> 6;
  if (wid >= N) return;
  int lane = threadIdx.x & 63;
  int beg = ptr[wid], end = ptr[wid + 1];
  float acc = 0.f;
  for (int cb = beg; cb < end; cb += 64) {
    int nv = min(64, end - cb);
    float wgt = 0.f; int entL = 0;
    if (lane < nv) {
      u32 e = entries[cb + lane]; entL = (int)e;
      if (e & (1u << 30)) wgt = dinv1[e & 0x3FFFFFFFu];
    }
    for (int i = 0; i < nv; ++i) {
      float w = __shfl(wgt, i, 64);
      if (w != 0.f) {
        int s = __shfl(entL, i, 64) & 0x3FFFFFFF;
        acc = fmaf(w, bf2f(h1b[(size_t)s * 64 + lane]), acc);
      }
    }
  }
  float dv = dinv1[wid];
  acc = fmaf(dv, bf2f(h1b[(size_t)wid * 64 + lane]), acc);  // self loop
  float o = fmaf(dv, acc, b1[lane]);
  o = fmaxf(o, 0.f);
  float ss = o * o;
#pragma unroll
  for (int off = 32; off > 0; off >>= 1) ss += __shfl_xor(ss, off, 64);
  float scale = 1.f / fmaxf(sqrtf(ss), 1e-12f);
  hn[(size_t)wid * 64 + lane] = o * scale;
}

// ---------------- conv2: aggregate + bias -> out ----------------
__global__ __launch_bounds__(256) void k_conv2(const int* __restrict__ ptr, const u32* __restrict__ entries,
                                               const float* __restrict__ dinv2, const u32* __restrict__ h2u,
                                               const float* __restrict__ b2, float* __restrict__ out, int N) {
  int wid = (blockIdx.x * 256 + threadIdx.x) >> 6;
  if (wid >= N) return;
  int lane = threadIdx.x & 63;
  int beg = ptr[wid], end = ptr[wid + 1];
  float a0 = 0.f, a1 = 0.f;
  for (int cb = beg; cb < end; cb += 64) {
    int nv = min(64, end - cb);
    float wgt = 0.f; int entL = 0;
    if (lane < nv) {
      u32 e = entries[cb + lane]; entL = (int)e;
      if (e & (1u << 31)) wgt = dinv2[e & 0x3FFFFFFFu];
    }
    for (int i = 0; i < nv; ++i) {
      float w = __shfl(wgt, i, 64);
      if (w != 0.f) {
        u32 s = (u32)__shfl(entL, i, 64) & 0x3FFFFFFFu;
        u32 u = h2u[(size_t)s * 64 + lane];
        a0 = fmaf(w, __uint_as_float(u << 16), a0);
        a1 = fmaf(w, __uint_as_float(u & 0xFFFF0000u), a1);
      }
    }
  }
  float dv = dinv2[wid];
  u32 u = h2u[(size_t)wid * 64 + lane];
  a0 = fmaf(dv, __uint_as_float(u << 16), a0);
  a1 = fmaf(dv, __uint_as_float(u & 0xFFFF0000u), a1);
  float2 bb = ((const float2*)b2)[lane];
  float2 res; res.x = fmaf(dv, a0, bb.x); res.y = fmaf(dv, a1, bb.y);
  ((float2*)out)[(size_t)wid * 64 + lane] = res;
}

// ---------------- launch ----------------
extern "C" void kernel_launch(void* const* d_in, const int* in_sizes, int n_in,
                              void* d_out, int out_size, void* d_ws, size_t ws_size,
                              hipStream_t stream) {
  const float* x  = (const float*)d_in[0];
  const int*   ei = (const int*)d_in[1];
  const float* W1 = (const float*)d_in[2];
  const float* b1 = (const float*)d_in[3];
  const float* W2 = (const float*)d_in[4];
  const float* b2 = (const float*)d_in[5];
  const int N = in_sizes[0] / 256;
  const int E = in_sizes[1] / 2;
  const int nb = (N + 511) >> 9;   // dst buckets (98 for N=50000; code assumes <=128)

  // JAX: key(42) -> split -> sk1, sk2
  u32 sk1a, sk1b, sk2a, sk2b;
  tf2x32(0u, 42u, 0u, 0u, sk1a, sk1b);
  tf2x32(0u, 42u, 0u, 1u, sk2a, sk2b);

  // workspace layout (256B aligned slabs)
  char* p = (char*)d_ws;
  auto alloc = [&](size_t bytes) { char* r = p; p += (bytes + 255) & ~(size_t)255; return r; };
  // --- zero-init group (contiguous) ---
  int* outdeg      = (int*)alloc((size_t)N * 4);
  int* bucketCount = (int*)alloc(128 * 4);
  int* hcbA        = (int*)alloc((size_t)(1 + HMAX) * 4);
  int* hcbB        = (int*)alloc((size_t)(1 + HMAX) * 4);
  char* zero_end = p;
  // --- 0xFF group (contiguous) ---
  int* heavyA      = (int*)alloc((size_t)N * 4);
  int* heavyB      = (int*)alloc((size_t)N * 4);
  char* ff_end = p;
  // --- rest ---
  unsigned char* mask = (unsigned char*)alloc((size_t)E);
  u16* h1b      = (u16*)alloc((size_t)N * 64 * 2);
  float* hn     = (float*)alloc((size_t)N * 64 * 4);
  u16* h2b      = (u16*)alloc((size_t)N * 128 * 2);
  float* dinv1  = (float*)alloc((size_t)N * 4);
  float* dinv2  = (float*)alloc((size_t)N * 4);
  int* dptr     = (int*)alloc((size_t)(N + 1) * 4);
  int* bucketBase = (int*)alloc(129 * 4);
  int* bucketCur  = (int*)alloc(128 * 4);
  u32* records  = (u32*)alloc((size_t)E * 4);
  u32* entries  = (u32*)alloc((size_t)E * 4);
  u64* bukA     = (u64*)alloc((size_t)HMAX * MAXD * 8);
  u64* bukB     = (u64*)alloc((size_t)HMAX * MAXD * 8);

  int* hcA = hcbA; int* bcA = hcbA + 1;
  int* hcB = hcbB; int* bcB = hcbB + 1;

  const int gE = (E + 255) / 256;
  const int gN = (N + 255) / 256;

  hipMemsetAsync(outdeg, 0x00, (size_t)(zero_end - (char*)outdeg), stream);
  hipMemsetAsync(heavyA, 0xFF, (size_t)(ff_end - (char*)heavyA), stream);
  hipMemsetAsync(mask, 0x03, (size_t)E, stream);

  k_hist0<<<(E + H0CHUNK - 1) / H0CHUNK, 256, 0, stream>>>(ei, outdeg, bucketCount, E, nb);
  k_scanbk<<<1, 64, 0, stream>>>(bucketCount, bucketBase, bucketCur, dptr, nb, N);
  k_heavy2<<<gN, 256, 0, stream>>>(outdeg, heavyA, heavyB, hcA, hcB, N);
  k_bfill2<<<gE, 256, 0, stream>>>(ei, heavyA, heavyB, bcA, bukA, bcB, bukB, E, sk1a, sk1b, sk2a, sk2b);
  k_rank<<<HMAX / 4, 256, 0, stream>>>(hcA, bcA, bukA, mask, 100, 0x1);
  k_rank<<<HMAX / 4, 256, 0, stream>>>(hcB, bcB, bukB, mask, 50, 0x2);
  k_phase1<<<(E + P1CHUNK - 1) / P1CHUNK, 256, 0, stream>>>(ei, mask, bucketCur, records, E);
  k_phase2<<<nb, 256, 0, stream>>>(bucketBase, records, entries, dptr, dinv1, dinv2, N);

  k_gemm1<<<(N + 15) / 16, 256, 0, stream>>>(x, W1, h1b, N);
  k_conv1<<<(N * 64 + 255) / 256, 256, 0, stream>>>(dptr, entries, dinv1, h1b, b1, hn, N);
  k_gemm2<<<(N + 7) / 8, 256, 0, stream>>>(hn, W2, h2b, N);
  k_conv2<<<(N * 64 + 255) / 256, 256, 0, stream>>>(dptr, entries, dinv2, (const u32*)h2b, b2,
                                                    (float*)d_out, N);
}

// Round 3
// 413.776 us; speedup vs baseline: 2.0171x; 1.4005x over previous
//
#include <hip/hip_runtime.h>

typedef unsigned int u32;
typedef unsigned short u16;
typedef unsigned long long u64;
typedef __attribute__((ext_vector_type(8))) short bh8;   // 8 bf16 (4 VGPRs) MFMA frag
typedef __attribute__((ext_vector_type(4))) float f4;    // 4 fp32 acc

#define HMAX 1024   // max heavy (deg>S) nodes tracked; expected ~65
#define MAXD 128    // max out-degree bucketed; expected max ~58

__device__ inline f4 mfma16(bh8 a, bh8 b, f4 c) {
  return __builtin_amdgcn_mfma_f32_16x16x32_bf16(a, b, c, 0, 0, 0);
}

// ---------------- threefry2x32 (exact JAX cipher) ----------------
__host__ __device__ inline void tf2x32(u32 k0, u32 k1, u32 x0, u32 x1, u32& o0, u32& o1) {
  u32 ks2 = k0 ^ k1 ^ 0x1BD11BDAu;
#define ROTL32(x,d) (((x)<<(d))|((x)>>(32-(d))))
#define TFR(r) { x0 += x1; x1 = ROTL32(x1,(r)); x1 ^= x0; }
  x0 += k0; x1 += k1;
  TFR(13) TFR(15) TFR(26) TFR(6)
  x0 += k1; x1 += ks2 + 1u;
  TFR(17) TFR(29) TFR(16) TFR(24)
  x0 += ks2; x1 += k0 + 2u;
  TFR(13) TFR(15) TFR(26) TFR(6)
  x0 += k0; x1 += k1 + 3u;
  TFR(17) TFR(29) TFR(16) TFR(24)
  x0 += k1; x1 += ks2 + 4u;
  TFR(13) TFR(15) TFR(26) TFR(6)
  x0 += ks2; x1 += k0 + 5u;
  o0 = x0; o1 = x1;
#undef TFR
#undef ROTL32
}

__device__ inline u16 f2bf(float f) {      // round-to-nearest-even (finite inputs)
  u32 u = __float_as_uint(f);
  return (u16)((u + 0x7FFFu + ((u >> 16) & 1u)) >> 16);
}

// ---------------- weight pre-transpose to bf16 n-major ----------------
__global__ __launch_bounds__(256) void k_prep(const float* __restrict__ W1, const float* __restrict__ W2,
                                              u16* __restrict__ W1t, u16* __restrict__ W2t) {
  int t = blockIdx.x * 256 + threadIdx.x;   // grid 4 x 256
  for (int e = t; e < 256 * 64; e += 1024) {
    int n = e & 63, k = e >> 6;
    W1t[n * 256 + k] = f2bf(W1[k * 64 + n]);
  }
  for (int e = t; e < 64 * 128; e += 1024) {
    int n = e & 127, k = e >> 7;
    W2t[n * 64 + k] = f2bf(W2[k * 128 + n]);
  }
}

// ---------------- phase 0: outdeg + dst-bucket histogram ----------------
#define H0CHUNK 4096
__global__ __launch_bounds__(256) void k_hist0(const int* __restrict__ ei, int* __restrict__ outdeg,
                                               int* __restrict__ bucketCount, int E, int nb) {
  __shared__ u32 hist[128];
  int t = threadIdx.x;
  if (t < 128) hist[t] = 0;
  __syncthreads();
  int lo = blockIdx.x * H0CHUNK;
  int hi = min(lo + H0CHUNK, E);
  for (int i = lo + t; i < hi; i += 256) {
    int s = ei[i];
    int d = ei[E + i];
    atomicAdd(&outdeg[s], 1);
    atomicAdd(&hist[d >> 9], 1u);
  }
  __syncthreads();
  if (t < nb && hist[t]) atomicAdd(&bucketCount[t], (int)hist[t]);
}

// ---------------- tiny scan: bucketCount -> bucketBase / bucketCur ----------------
__global__ void k_scanbk(const int* __restrict__ bucketCount, int* __restrict__ bucketBase,
                         int* __restrict__ bucketCur, int* __restrict__ dptr, int nb, int N) {
  if (threadIdx.x == 0) {
    int s = 0;
    for (int i = 0; i < nb; ++i) { bucketBase[i] = s; bucketCur[i] = s; s += bucketCount[i]; }
    bucketBase[nb] = s;
    dptr[N] = s;   // == E
  }
}

// ---------------- heavy detection (both sample phases in one sweep) ----------------
__global__ __launch_bounds__(256) void k_heavy2(const int* __restrict__ outdeg,
                                                int* __restrict__ hA, int* __restrict__ hB,
                                                int* __restrict__ hcA, int* __restrict__ hcB, int N) {
  int v = blockIdx.x * 256 + threadIdx.x;
  if (v >= N) return;
  int d = outdeg[v];
  if (d > 100) { int id = atomicAdd(hcA, 1); if (id < HMAX) hA[v] = id; }
  if (d > 50)  { int id = atomicAdd(hcB, 1); if (id < HMAX) hB[v] = id; }
}

// ---------------- bucket heavy edges with PRNG keys (both phases, one sweep) ----------------
__global__ __launch_bounds__(256) void k_bfill2(const int* __restrict__ ei,
                                                const int* __restrict__ hA, const int* __restrict__ hB,
                                                int* __restrict__ bcA, u64* __restrict__ bukA,
                                                int* __restrict__ bcB, u64* __restrict__ bukB,
                                                int E, u32 kaA, u32 kbA, u32 kaB, u32 kbB) {
  int e = blockIdx.x * 256 + threadIdx.x;
  if (e >= E) return;
  int s = ei[e];
  int ia = hA[s], ib = hB[s];
  if (ia >= 0 && ia < HMAX) {
    u32 w0, w1; tf2x32(kaA, kbA, 0u, (u32)e, w0, w1);
    u32 r = (w0 ^ w1) >> 9;
    int slot = atomicAdd(&bcA[ia], 1);
    if (slot < MAXD) bukA[(size_t)ia * MAXD + slot] = ((u64)r << 32) | (u32)e;
  }
  if (ib >= 0 && ib < HMAX) {
    u32 w0, w1; tf2x32(kaB, kbB, 0u, (u32)e, w0, w1);
    u32 r = (w0 ^ w1) >> 9;
    int slot = atomicAdd(&bcB[ib], 1);
    if (slot < MAXD) bukB[(size_t)ib * MAXD + slot] = ((u64)r << 32) | (u32)e;
  }
}

// rank each bucketed edge by (key, idx); drop rank >= S  (clears `bit` in mask)
__global__ __launch_bounds__(256) void k_rank(const int* __restrict__ hcount, const int* __restrict__ bcount,
                                              const u64* __restrict__ bucket, unsigned char* __restrict__ mask,
                                              int S, int bit) {
  int wid = (blockIdx.x * 256 + threadIdx.x) >> 6;
  int lane = threadIdx.x & 63;
  int hc = hcount[0]; if (hc > HMAX) hc = HMAX;
  if (wid >= hc) return;
  int d = bcount[wid]; if (d > MAXD) d = MAXD;
  const u64* B = bucket + (size_t)wid * MAXD;
  for (int i = lane; i < d; i += 64) {
    u64 ki = B[i];
    int rank = 0;
    for (int j = 0; j < d; ++j) rank += (B[j] < ki) ? 1 : 0;
    if (rank >= S) {
      u32 e = (u32)ki;
      mask[e] = (unsigned char)(mask[e] & ~bit);
    }
  }
}

// ---------------- phase 1: binned scatter of edge records ----------------
// record = src(0:15) | dstlow(16:24) | m1(25) | m2(26)
#define P1CHUNK 8192
__global__ __launch_bounds__(256) void k_phase1(const int* __restrict__ ei,
                                                const unsigned char* __restrict__ mask,
                                                int* __restrict__ bucketCur, u32* __restrict__ records, int E) {
  __shared__ u32 lc[128];
  __shared__ u32 lbase[128];
  int t = threadIdx.x;
  if (t < 128) lc[t] = 0;
  __syncthreads();
  int lo = blockIdx.x * P1CHUNK;
  int hi = min(lo + P1CHUNK, E);
  for (int i = lo + t; i < hi; i += 256) {
    int d = ei[E + i];
    atomicAdd(&lc[d >> 9], 1u);
  }
  __syncthreads();
  if (t < 128) {
    u32 c = lc[t];
    if (c) lbase[t] = (u32)atomicAdd(&bucketCur[t], (int)c);
    lc[t] = 0;
  }
  __syncthreads();
  for (int i = lo + t; i < hi; i += 256) {
    int s = ei[i];
    int d = ei[E + i];
    unsigned char m = mask[i];
    int bk = d >> 9;
    u32 slot = lbase[bk] + atomicAdd(&lc[bk], 1u);
    records[slot] = (u32)s | ((u32)(d & 511) << 16) | ((u32)(m & 3u) << 25);
  }
}

// ---------------- phase 2: per-bucket counting sort -> entries/dptr/dinv ----------------
__global__ __launch_bounds__(256) void k_phase2(const int* __restrict__ bucketBase,
                                                const u32* __restrict__ records,
                                                u32* __restrict__ entries, int* __restrict__ dptr,
                                                float* __restrict__ dinv1, float* __restrict__ dinv2, int N) {
  int b = blockIdx.x;
  int lo = bucketBase[b], hi = bucketBase[b + 1];
  __shared__ u32 cnt[512];
  __shared__ u32 ws4[4];
  int t = threadIdx.x;
  cnt[t] = 0; cnt[t + 256] = 0;
  __syncthreads();
  for (int i = lo + t; i < hi; i += 256) {
    u32 r = records[i];
    u32 dl = (r >> 16) & 511u;
    u32 add = 1u + (((r >> 25) & 1u) << 10) + (((r >> 26) & 1u) << 20);
    atomicAdd(&cnt[dl], add);
  }
  __syncthreads();
  u32 c0 = cnt[2 * t], c1 = cnt[2 * t + 1];
  u32 n0 = c0 & 1023u, n1 = c1 & 1023u;
  u32 pair = n0 + n1;
  int lane = t & 63, w = t >> 6;
  u32 incl = pair;
  for (int off = 1; off < 64; off <<= 1) {
    u32 nbv = (u32)__shfl_up((int)incl, off, 64);
    if (lane >= off) incl += nbv;
  }
  if (lane == 63) ws4[w] = incl;
  __syncthreads();
  if (t == 0) { u32 s = 0; for (int k = 0; k < 4; ++k) { u32 x = ws4[k]; ws4[k] = s; s += x; } }
  __syncthreads();
  u32 excl = incl - pair + ws4[w];
  int v0 = b * 512 + 2 * t;
  if (v0 < N) {
    dptr[v0] = lo + (int)excl;
    dinv1[v0] = 1.0f / sqrtf((float)(((c0 >> 10) & 1023u) + 1u));
    dinv2[v0] = 1.0f / sqrtf((float)(((c0 >> 20) & 1023u) + 1u));
  }
  if (v0 + 1 < N) {
    dptr[v0 + 1] = lo + (int)(excl + n0);
    dinv1[v0 + 1] = 1.0f / sqrtf((float)(((c1 >> 10) & 1023u) + 1u));
    dinv2[v0 + 1] = 1.0f / sqrtf((float)(((c1 >> 20) & 1023u) + 1u));
  }
  __syncthreads();
  cnt[2 * t] = excl;
  cnt[2 * t + 1] = excl + n0;
  __syncthreads();
  for (int i = lo + t; i < hi; i += 256) {
    u32 r = records[i];
    u32 dl = (r >> 16) & 511u;
    u32 slot = atomicAdd(&cnt[dl], 1u);
    entries[lo + slot] = (r & 0xFFFFu) | ((r & (1u << 25)) ? (1u << 30) : 0u)
                                       | ((r & (1u << 26)) ? (1u << 31) : 0u);
  }
}

// ---------------- gemm1: h1 = bf16(x) @ bf16(W1), MFMA 16x16x32, K-split staging ----------------
#define G1S 136   // LDS row stride (128 + 8 pad) -> 2-way bank alias only (free)
__global__ __launch_bounds__(256) void k_gemm1(const float* __restrict__ x, const u16* __restrict__ W1t,
                                               u16* __restrict__ h1b, int N) {
  __shared__ u16 xs[64 * G1S];
  __shared__ u16 ws[64 * G1S];
  int t = threadIdx.x;
  int wv = t >> 6, lane = t & 63;
  int qd = lane >> 4, md = lane & 15;
  int m0 = blockIdx.x * 64;
  f4 acc[4] = {};
  for (int ks = 0; ks < 256; ks += 128) {
    __syncthreads();
#pragma unroll
    for (int i = 0; i < 8; ++i) {               // stage x[m0..+63][ks..+127] -> bf16 LDS
      int f = t + 256 * i;                       // 2048 float4s
      int r = f >> 5, c4 = f & 31;
      int grow = m0 + r; if (grow >= N) grow = N - 1;
      float4 v = ((const float4*)x)[(size_t)grow * 64 + (ks >> 2) + c4];
      u32 p0 = (u32)f2bf(v.x) | ((u32)f2bf(v.y) << 16);
      u32 p1 = (u32)f2bf(v.z) | ((u32)f2bf(v.w) << 16);
      *((uint2*)(xs + r * G1S + c4 * 4)) = make_uint2(p0, p1);
    }
#pragma unroll
    for (int i = 0; i < 4; ++i) {               // stage W1t[0..63][ks..+127]
      int cc = t + 256 * i;                      // 1024 chunks of 8 u16
      int n = cc >> 4, kc = (cc & 15) * 8;
      *((uint4*)(ws + n * G1S + kc)) = *((const uint4*)(W1t + n * 256 + ks + kc));
    }
    __syncthreads();
#pragma unroll
    for (int kk = 0; kk < 128; kk += 32) {
      bh8 af = *((const bh8*)(xs + (16 * wv + md) * G1S + kk + qd * 8));
#pragma unroll
      for (int nt = 0; nt < 4; ++nt) {
        bh8 bf = *((const bh8*)(ws + (nt * 16 + md) * G1S + kk + qd * 8));
        acc[nt] = mfma16(af, bf, acc[nt]);
      }
    }
  }
#pragma unroll
  for (int nt = 0; nt < 4; ++nt)
#pragma unroll
    for (int r = 0; r < 4; ++r) {
      int row = m0 + 16 * wv + qd * 4 + r;
      if (row < N) h1b[(size_t)row * 64 + nt * 16 + md] = f2bf(acc[nt][r]);
    }
}

// ---------------- gemm2: h2 = bf16(hn) @ bf16(W2), MFMA ----------------
#define G2S 72
__global__ __launch_bounds__(256) void k_gemm2(const float* __restrict__ hn, const u16* __restrict__ W2t,
                                               u16* __restrict__ h2b, int N) {
  __shared__ u16 hs[64 * G2S];
  __shared__ u16 ws[128 * G2S];
  int t = threadIdx.x;
  int wv = t >> 6, lane = t & 63;
  int qd = lane >> 4, md = lane & 15;
  int m0 = blockIdx.x * 64;
#pragma unroll
  for (int i = 0; i < 4; ++i) {                 // stage hn (fp32 -> bf16)
    int f = t + 256 * i;                         // 1024 float4s
    int r = f >> 4, c4 = f & 15;
    int grow = m0 + r; if (grow >= N) grow = N - 1;
    float4 v = ((const float4*)hn)[(size_t)grow * 16 + c4];
    u32 p0 = (u32)f2bf(v.x) | ((u32)f2bf(v.y) << 16);
    u32 p1 = (u32)f2bf(v.z) | ((u32)f2bf(v.w) << 16);
    *((uint2*)(hs + r * G2S + c4 * 4)) = make_uint2(p0, p1);
  }
#pragma unroll
  for (int i = 0; i < 4; ++i) {                 // stage W2t (128x64 u16)
    int cc = t + 256 * i;
    int n = cc >> 3, kc = (cc & 7) * 8;
    *((uint4*)(ws + n * G2S + kc)) = *((const uint4*)(W2t + n * 64 + kc));
  }
  __syncthreads();
  f4 acc[8] = {};
#pragma unroll
  for (int kk = 0; kk < 64; kk += 32) {
    bh8 af = *((const bh8*)(hs + (16 * wv + md) * G2S + kk + qd * 8));
#pragma unroll
    for (int nt = 0; nt < 8; ++nt) {
      bh8 bf = *((const bh8*)(ws + (nt * 16 + md) * G2S + kk + qd * 8));
      acc[nt] = mfma16(af, bf, acc[nt]);
    }
  }
#pragma unroll
  for (int nt = 0; nt < 8; ++nt)
#pragma unroll
    for (int r = 0; r < 4; ++r) {
      int row = m0 + 16 * wv + qd * 4 + r;
      if (row < N) h2b[(size_t)row * 128 + nt * 16 + md] = f2bf(acc[nt][r]);
    }
}

// ---------------- conv1: aggregate + bias + relu + L2 normalize ----------------
// wave per dst; lane halves gather 2 src rows/iter (u32 = 2 channels per lane)
__global__ __launch_bounds__(256) void k_conv1(const int* __restrict__ ptr, const u32* __restrict__ entries,
                                               const float* __restrict__ dinv1, const u32* __restrict__ h1u,
                                               const float* __restrict__ b1, float* __restrict__ hn, int N) {
  int wid = (blockIdx.x * 256 + threadIdx.x) >> 6;
  if (wid >= N) return;
  int lane = threadIdx.x & 63;
  int lp = lane & 31, hf = lane >> 5;
  int beg = ptr[wid], end = ptr[wid + 1];
  float a0 = 0.f, a1 = 0.f;
  for (int cb = beg; cb < end; cb += 64) {
    int idx = cb + lane;
    float wgt = 0.f; int s = 0;
    if (idx < end) {
      u32 e = entries[idx];
      s = (int)(e & 0xFFFFu);
      if (e & (1u << 30)) wgt = dinv1[s];
    }
    int half = (min(64, end - cb) + 1) >> 1;
    for (int i = 0; i < half; ++i) {
      int j = 2 * i + hf;
      float w = __shfl(wgt, j, 64);
      int sj  = __shfl(s, j, 64);
      u32 u = h1u[(size_t)sj * 32 + lp];
      a0 = fmaf(w, __uint_as_float(u << 16), a0);
      a1 = fmaf(w, __uint_as_float(u & 0xFFFF0000u), a1);
    }
  }
  a0 += __shfl_xor(a0, 32, 64);
  a1 += __shfl_xor(a1, 32, 64);
  float dv = dinv1[wid];
  u32 uo = h1u[(size_t)wid * 32 + lp];
  a0 = fmaf(dv, __uint_as_float(uo << 16), a0);
  a1 = fmaf(dv, __uint_as_float(uo & 0xFFFF0000u), a1);
  float2 bb = ((const float2*)b1)[lp];
  float o0 = fmaxf(fmaf(dv, a0, bb.x), 0.f);
  float o1 = fmaxf(fmaf(dv, a1, bb.y), 0.f);
  float ss = fmaf(o0, o0, o1 * o1);
#pragma unroll
  for (int off = 16; off > 0; off >>= 1) ss += __shfl_xor(ss, off, 32);
  float scale = 1.f / fmaxf(sqrtf(ss), 1e-12f);
  if (lane < 32) ((float2*)hn)[(size_t)wid * 32 + lp] = make_float2(o0 * scale, o1 * scale);
}

// ---------------- conv2: aggregate + bias -> out ----------------
// wave per dst; lane halves gather 2 src rows/iter (uint2 = 4 bf16 channels per lane)
__global__ __launch_bounds__(256) void k_conv2(const int* __restrict__ ptr, const u32* __restrict__ entries,
                                               const float* __restrict__ dinv2, const uint2* __restrict__ h2v,
                                               const float* __restrict__ b2, float* __restrict__ out, int N) {
  int wid = (blockIdx.x * 256 + threadIdx.x) >> 6;
  if (wid >= N) return;
  int lane = threadIdx.x & 63;
  int lp = lane & 31, hf = lane >> 5;
  int beg = ptr[wid], end = ptr[wid + 1];
  float a0 = 0.f, a1 = 0.f, a2 = 0.f, a3 = 0.f;
  for (int cb = beg; cb < end; cb += 64) {
    int idx = cb + lane;
    float wgt = 0.f; int s = 0;
    if (idx < end) {
      u32 e = entries[idx];
      s = (int)(e & 0xFFFFu);
      if (e & (1u << 31)) wgt = dinv2[s];
    }
    int half = (min(64, end - cb) + 1) >> 1;
    for (int i = 0; i < half; ++i) {
      int j = 2 * i + hf;
      float w = __shfl(wgt, j, 64);
      int sj  = __shfl(s, j, 64);
      uint2 uv = h2v[(size_t)sj * 32 + lp];
      a0 = fmaf(w, __uint_as_float(uv.x << 16), a0);
      a1 = fmaf(w, __uint_as_float(uv.x & 0xFFFF0000u), a1);
      a2 = fmaf(w, __uint_as_float(uv.y << 16), a2);
      a3 = fmaf(w, __uint_as_float(uv.y & 0xFFFF0000u), a3);
    }
  }
  a0 += __shfl_xor(a0, 32, 64);
  a1 += __shfl_xor(a1, 32, 64);
  a2 += __shfl_xor(a2, 32, 64);
  a3 += __shfl_xor(a3, 32, 64);
  float dv = dinv2[wid];
  uint2 uo = h2v[(size_t)wid * 32 + lp];
  a0 = fmaf(dv, __uint_as_float(uo.x << 16), a0);
  a1 = fmaf(dv, __uint_as_float(uo.x & 0xFFFF0000u), a1);
  a2 = fmaf(dv, __uint_as_float(uo.y << 16), a2);
  a3 = fmaf(dv, __uint_as_float(uo.y & 0xFFFF0000u), a3);
  float4 bb = ((const float4*)b2)[lp];
  float4 res;
  res.x = fmaf(dv, a0, bb.x);
  res.y = fmaf(dv, a1, bb.y);
  res.z = fmaf(dv, a2, bb.z);
  res.w = fmaf(dv, a3, bb.w);
  if (lane < 32) ((float4*)out)[(size_t)wid * 32 + lp] = res;
}

// ---------------- launch ----------------
extern "C" void kernel_launch(void* const* d_in, const int* in_sizes, int n_in,
                              void* d_out, int out_size, void* d_ws, size_t ws_size,
                              hipStream_t stream) {
  const float* x  = (const float*)d_in[0];
  const int*   ei = (const int*)d_in[1];
  const float* W1 = (const float*)d_in[2];
  const float* b1 = (const float*)d_in[3];
  const float* W2 = (const float*)d_in[4];
  const float* b2 = (const float*)d_in[5];
  const int N = in_sizes[0] / 256;
  const int E = in_sizes[1] / 2;
  const int nb = (N + 511) >> 9;   // dst buckets (98 for N=50000)

  u32 sk1a, sk1b, sk2a, sk2b;
  tf2x32(0u, 42u, 0u, 0u, sk1a, sk1b);
  tf2x32(0u, 42u, 0u, 1u, sk2a, sk2b);

  char* p = (char*)d_ws;
  auto alloc = [&](size_t bytes) { char* r = p; p += (bytes + 255) & ~(size_t)255; return r; };
  // --- zero-init group (contiguous) ---
  int* outdeg      = (int*)alloc((size_t)N * 4);
  int* bucketCount = (int*)alloc(128 * 4);
  int* hcbA        = (int*)alloc((size_t)(1 + HMAX) * 4);
  int* hcbB        = (int*)alloc((size_t)(1 + HMAX) * 4);
  char* zero_end = p;
  // --- 0xFF group (contiguous) ---
  int* heavyA      = (int*)alloc((size_t)N * 4);
  int* heavyB      = (int*)alloc((size_t)N * 4);
  char* ff_end = p;
  // --- rest ---
  unsigned char* mask = (unsigned char*)alloc((size_t)E);
  u16* h1b      = (u16*)alloc((size_t)N * 64 * 2);
  float* hn     = (float*)alloc((size_t)N * 64 * 4);
  u16* h2b      = (u16*)alloc((size_t)N * 128 * 2);
  float* dinv1  = (float*)alloc((size_t)N * 4);
  float* dinv2  = (float*)alloc((size_t)N * 4);
  int* dptr     = (int*)alloc((size_t)(N + 1) * 4);
  int* bucketBase = (int*)alloc(129 * 4);
  int* bucketCur  = (int*)alloc(128 * 4);
  u32* records  = (u32*)alloc((size_t)E * 4);
  u32* entries  = (u32*)alloc((size_t)E * 4);
  u64* bukA     = (u64*)alloc((size_t)HMAX * MAXD * 8);
  u64* bukB     = (u64*)alloc((size_t)HMAX * MAXD * 8);
  u16* W1t      = (u16*)alloc(256 * 64 * 2);
  u16* W2t      = (u16*)alloc(64 * 128 * 2);

  int* hcA = hcbA; int* bcA = hcbA + 1;
  int* hcB = hcbB; int* bcB = hcbB + 1;

  const int gE = (E + 255) / 256;
  const int gN = (N + 255) / 256;

  hipMemsetAsync(outdeg, 0x00, (size_t)(zero_end - (char*)outdeg), stream);
  hipMemsetAsync(heavyA, 0xFF, (size_t)(ff_end - (char*)heavyA), stream);
  hipMemsetAsync(mask, 0x03, (size_t)E, stream);

  k_prep<<<4, 256, 0, stream>>>(W1, W2, W1t, W2t);
  k_hist0<<<(E + H0CHUNK - 1) / H0CHUNK, 256, 0, stream>>>(ei, outdeg, bucketCount, E, nb);
  k_scanbk<<<1, 64, 0, stream>>>(bucketCount, bucketBase, bucketCur, dptr, nb, N);
  k_heavy2<<<gN, 256, 0, stream>>>(outdeg, heavyA, heavyB, hcA, hcB, N);
  k_bfill2<<<gE, 256, 0, stream>>>(ei, heavyA, heavyB, bcA, bukA, bcB, bukB, E, sk1a, sk1b, sk2a, sk2b);
  k_rank<<<HMAX / 4, 256, 0, stream>>>(hcA, bcA, bukA, mask, 100, 0x1);
  k_rank<<<HMAX / 4, 256, 0, stream>>>(hcB, bcB, bukB, mask, 50, 0x2);
  k_phase1<<<(E + P1CHUNK - 1) / P1CHUNK, 256, 0, stream>>>(ei, mask, bucketCur, records, E);
  k_phase2<<<nb, 256, 0, stream>>>(bucketBase, records, entries, dptr, dinv1, dinv2, N);

  k_gemm1<<<(N + 63) / 64, 256, 0, stream>>>(x, W1t, h1b, N);
  k_conv1<<<(N * 64 + 255) / 256, 256, 0, stream>>>(dptr, entries, dinv1, (const u32*)h1b, b1, hn, N);
  k_gemm2<<<(N + 63) / 64, 256, 0, stream>>>(hn, W2t, h2b, N);
  k_conv2<<<(N * 64 + 255) / 256, 256, 0, stream>>>(dptr, entries, dinv2, (const uint2*)h2b, b2,
                                                    (float*)d_out, N);
}

// Round 4
// 397.420 us; speedup vs baseline: 2.1001x; 1.0412x over previous
//
#include <hip/hip_runtime.h>

typedef unsigned int u32;
typedef unsigned short u16;
typedef unsigned long long u64;
typedef __attribute__((ext_vector_type(8))) short bh8;   // 8 bf16 (4 VGPRs) MFMA frag
typedef __attribute__((ext_vector_type(4))) float f4;    // 4 fp32 acc

#define HMAX 1024   // max heavy (deg>S) nodes tracked; expected ~65
#define MAXD 128    // max out-degree bucketed; expected max ~58
#define SB_CAP 24576  // src-bin capacity: mean 16384, sigma ~127 -> +64 sigma
#define SBCHUNK 2048

__device__ inline f4 mfma16(bh8 a, bh8 b, f4 c) {
  return __builtin_amdgcn_mfma_f32_16x16x32_bf16(a, b, c, 0, 0, 0);
}

// ---------------- threefry2x32 (exact JAX cipher) ----------------
__host__ __device__ inline void tf2x32(u32 k0, u32 k1, u32 x0, u32 x1, u32& o0, u32& o1) {
  u32 ks2 = k0 ^ k1 ^ 0x1BD11BDAu;
#define ROTL32(x,d) (((x)<<(d))|((x)>>(32-(d))))
#define TFR(r) { x0 += x1; x1 = ROTL32(x1,(r)); x1 ^= x0; }
  x0 += k0; x1 += k1;
  TFR(13) TFR(15) TFR(26) TFR(6)
  x0 += k1; x1 += ks2 + 1u;
  TFR(17) TFR(29) TFR(16) TFR(24)
  x0 += ks2; x1 += k0 + 2u;
  TFR(13) TFR(15) TFR(26) TFR(6)
  x0 += k0; x1 += k1 + 3u;
  TFR(17) TFR(29) TFR(16) TFR(24)
  x0 += k1; x1 += ks2 + 4u;
  TFR(13) TFR(15) TFR(26) TFR(6)
  x0 += ks2; x1 += k0 + 5u;
  o0 = x0; o1 = x1;
#undef TFR
#undef ROTL32
}

__device__ inline u16 f2bf(float f) {      // round-to-nearest-even (finite inputs)
  u32 u = __float_as_uint(f);
  return (u16)((u + 0x7FFFu + ((u >> 16) & 1u)) >> 16);
}

// ---------------- weight pre-transpose to bf16 n-major ----------------
__global__ __launch_bounds__(256) void k_prep(const float* __restrict__ W1, const float* __restrict__ W2,
                                              u16* __restrict__ W1t, u16* __restrict__ W2t) {
  int t = blockIdx.x * 256 + threadIdx.x;   // grid 4 x 256
  for (int e = t; e < 256 * 64; e += 1024) {
    int n = e & 63, k = e >> 6;
    W1t[n * 256 + k] = f2bf(W1[k * 64 + n]);
  }
  for (int e = t; e < 64 * 128; e += 1024) {
    int n = e & 127, k = e >> 7;
    W2t[n * 64 + k] = f2bf(W2[k * 128 + n]);
  }
}

// ---------------- src-binned record scatter + dst-bucket histogram ----------------
// src record = srclow9 (21:29) | edgeid (0:20)
__global__ __launch_bounds__(256) void k_srcbin(const int* __restrict__ ei,
                                                int* __restrict__ srcCnt, u32* __restrict__ srcRec,
                                                int* __restrict__ dstCnt, int E, int nb) {
  __shared__ u32 lsrc[128], ldst[128], lbase[128];
  int t = threadIdx.x;
  if (t < 128) { lsrc[t] = 0; ldst[t] = 0; }
  __syncthreads();
  int lo = blockIdx.x * SBCHUNK;
  int hi = min(lo + SBCHUNK, E);
  int sv[SBCHUNK / 256];
  int ci = 0;
  for (int i = lo + t; i < hi; i += 256) {
    int s = ei[i];
    int d = ei[E + i];
    sv[ci++] = s;
    atomicAdd(&lsrc[s >> 9], 1u);
    atomicAdd(&ldst[d >> 9], 1u);
  }
  __syncthreads();
  if (t < 128) {
    u32 c = lsrc[t];
    if (c) lbase[t] = (u32)atomicAdd(&srcCnt[t], (int)c);
    lsrc[t] = 0;
    if (ldst[t]) atomicAdd(&dstCnt[t], (int)ldst[t]);
  }
  __syncthreads();
  ci = 0;
  for (int i = lo + t; i < hi; i += 256) {
    int s = sv[ci++];
    int bk = s >> 9;
    u32 slot = lbase[bk] + atomicAdd(&lsrc[bk], 1u);
    if (slot < SB_CAP)
      srcRec[(size_t)bk * SB_CAP + slot] = ((u32)(s & 511) << 21) | (u32)i;
  }
}

// ---------------- per-src-bucket: out-degree count + heavy detect + PRNG bucketing ----------------
__global__ __launch_bounds__(256) void k_srcproc(const int* __restrict__ srcCnt, const u32* __restrict__ srcRec,
                                                 int* __restrict__ hcA, int* __restrict__ bcA, u64* __restrict__ bukA,
                                                 int* __restrict__ hcB, int* __restrict__ bcB, u64* __restrict__ bukB,
                                                 int N, u32 kaA, u32 kbA, u32 kaB, u32 kbB) {
  int bk = blockIdx.x;
  int cnt0 = min(srcCnt[bk], SB_CAP);
  __shared__ u32 cnt[512];
  __shared__ int idA[512], idB[512];
  int t = threadIdx.x;
  cnt[t] = 0; cnt[t + 256] = 0;
  __syncthreads();
  const u32* R = srcRec + (size_t)bk * SB_CAP;
  for (int i = t; i < cnt0; i += 256) atomicAdd(&cnt[R[i] >> 21], 1u);
  __syncthreads();
  for (int v = t; v < 512; v += 256) {
    idA[v] = -1; idB[v] = -1;
    int node = bk * 512 + v;
    if (node < N) {
      u32 dg = cnt[v];
      if (dg > 100u) { int id = atomicAdd(hcA, 1); if (id < HMAX) idA[v] = id; }
      if (dg > 50u)  { int id = atomicAdd(hcB, 1); if (id < HMAX) idB[v] = id; }
    }
  }
  __syncthreads();
  for (int i = t; i < cnt0; i += 256) {
    u32 r = R[i];
    int sl = (int)(r >> 21);
    u32 e = r & 0x1FFFFFu;
    int ib = idB[sl];
    if (ib >= 0) {
      u32 w0, w1; tf2x32(kaB, kbB, 0u, e, w0, w1);
      u32 key = (w0 ^ w1) >> 9;
      int slot = atomicAdd(&bcB[ib], 1);
      if (slot < MAXD) bukB[(size_t)ib * MAXD + slot] = ((u64)key << 32) | e;
      int ia = idA[sl];
      if (ia >= 0) {
        tf2x32(kaA, kbA, 0u, e, w0, w1);
        key = (w0 ^ w1) >> 9;
        slot = atomicAdd(&bcA[ia], 1);
        if (slot < MAXD) bukA[(size_t)ia * MAXD + slot] = ((u64)key << 32) | e;
      }
    }
  }
}

// ---------------- tiny scan: dstCnt -> bucketBase / bucketCur ----------------
__global__ void k_scanbk(const int* __restrict__ bucketCount, int* __restrict__ bucketBase,
                         int* __restrict__ bucketCur, int* __restrict__ dptr, int nb, int N) {
  if (threadIdx.x == 0) {
    int s = 0;
    for (int i = 0; i < nb; ++i) { bucketBase[i] = s; bucketCur[i] = s; s += bucketCount[i]; }
    bucketBase[nb] = s;
    dptr[N] = s;   // == E
  }
}

// rank each bucketed edge by (key, idx); drop rank >= S  (clears `bit` in mask)
__global__ __launch_bounds__(256) void k_rank(const int* __restrict__ hcount, const int* __restrict__ bcount,
                                              const u64* __restrict__ bucket, unsigned char* __restrict__ mask,
                                              int S, int bit) {
  int wid = (blockIdx.x * 256 + threadIdx.x) >> 6;
  int lane = threadIdx.x & 63;
  int hc = hcount[0]; if (hc > HMAX) hc = HMAX;
  if (wid >= hc) return;
  int d = bcount[wid]; if (d > MAXD) d = MAXD;
  const u64* B = bucket + (size_t)wid * MAXD;
  for (int i = lane; i < d; i += 64) {
    u64 ki = B[i];
    int rank = 0;
    for (int j = 0; j < d; ++j) rank += (B[j] < ki) ? 1 : 0;
    if (rank >= S) {
      u32 e = (u32)ki;
      mask[e] = (unsigned char)(mask[e] & ~bit);
    }
  }
}

// ---------------- phase 1: binned scatter of edge records ----------------
// record = src(0:15) | dstlow(16:24) | m1(25) | m2(26)
#define P1CHUNK 8192
__global__ __launch_bounds__(256) void k_phase1(const int* __restrict__ ei,
                                                const unsigned char* __restrict__ mask,
                                                int* __restrict__ bucketCur, u32* __restrict__ records, int E) {
  __shared__ u32 lc[128];
  __shared__ u32 lbase[128];
  int t = threadIdx.x;
  if (t < 128) lc[t] = 0;
  __syncthreads();
  int lo = blockIdx.x * P1CHUNK;
  int hi = min(lo + P1CHUNK, E);
  for (int i = lo + t; i < hi; i += 256) {
    int d = ei[E + i];
    atomicAdd(&lc[d >> 9], 1u);
  }
  __syncthreads();
  if (t < 128) {
    u32 c = lc[t];
    if (c) lbase[t] = (u32)atomicAdd(&bucketCur[t], (int)c);
    lc[t] = 0;
  }
  __syncthreads();
  for (int i = lo + t; i < hi; i += 256) {
    int s = ei[i];
    int d = ei[E + i];
    unsigned char m = mask[i];
    int bk = d >> 9;
    u32 slot = lbase[bk] + atomicAdd(&lc[bk], 1u);
    records[slot] = (u32)s | ((u32)(d & 511) << 16) | ((u32)(m & 3u) << 25);
  }
}

// ---------------- phase 2: per-bucket counting sort -> entries/dptr/dinv ----------------
__global__ __launch_bounds__(256) void k_phase2(const int* __restrict__ bucketBase,
                                                const u32* __restrict__ records,
                                                u32* __restrict__ entries, int* __restrict__ dptr,
                                                float* __restrict__ dinv1, float* __restrict__ dinv2, int N) {
  int b = blockIdx.x;
  int lo = bucketBase[b], hi = bucketBase[b + 1];
  __shared__ u32 cnt[512];
  __shared__ u32 ws4[4];
  int t = threadIdx.x;
  cnt[t] = 0; cnt[t + 256] = 0;
  __syncthreads();
  for (int i = lo + t; i < hi; i += 256) {
    u32 r = records[i];
    u32 dl = (r >> 16) & 511u;
    u32 add = 1u + (((r >> 25) & 1u) << 10) + (((r >> 26) & 1u) << 20);
    atomicAdd(&cnt[dl], add);
  }
  __syncthreads();
  u32 c0 = cnt[2 * t], c1 = cnt[2 * t + 1];
  u32 n0 = c0 & 1023u, n1 = c1 & 1023u;
  u32 pair = n0 + n1;
  int lane = t & 63, w = t >> 6;
  u32 incl = pair;
  for (int off = 1; off < 64; off <<= 1) {
    u32 nbv = (u32)__shfl_up((int)incl, off, 64);
    if (lane >= off) incl += nbv;
  }
  if (lane == 63) ws4[w] = incl;
  __syncthreads();
  if (t == 0) { u32 s = 0; for (int k = 0; k < 4; ++k) { u32 x = ws4[k]; ws4[k] = s; s += x; } }
  __syncthreads();
  u32 excl = incl - pair + ws4[w];
  int v0 = b * 512 + 2 * t;
  if (v0 < N) {
    dptr[v0] = lo + (int)excl;
    dinv1[v0] = 1.0f / sqrtf((float)(((c0 >> 10) & 1023u) + 1u));
    dinv2[v0] = 1.0f / sqrtf((float)(((c0 >> 20) & 1023u) + 1u));
  }
  if (v0 + 1 < N) {
    dptr[v0 + 1] = lo + (int)(excl + n0);
    dinv1[v0 + 1] = 1.0f / sqrtf((float)(((c1 >> 10) & 1023u) + 1u));
    dinv2[v0 + 1] = 1.0f / sqrtf((float)(((c1 >> 20) & 1023u) + 1u));
  }
  __syncthreads();
  cnt[2 * t] = excl;
  cnt[2 * t + 1] = excl + n0;
  __syncthreads();
  for (int i = lo + t; i < hi; i += 256) {
    u32 r = records[i];
    u32 dl = (r >> 16) & 511u;
    u32 slot = atomicAdd(&cnt[dl], 1u);
    entries[lo + slot] = (r & 0xFFFFu) | ((r & (1u << 25)) ? (1u << 30) : 0u)
                                       | ((r & (1u << 26)) ? (1u << 31) : 0u);
  }
}

// ---------------- gemm1: h1 = bf16(x) @ bf16(W1), MFMA 16x16x32, K-split staging ----------------
#define G1S 136   // LDS row stride (128 + 8 pad) -> 2-way bank alias only (free)
__global__ __launch_bounds__(256) void k_gemm1(const float* __restrict__ x, const u16* __restrict__ W1t,
                                               u16* __restrict__ h1b, int N) {
  __shared__ u16 xs[64 * G1S];
  __shared__ u16 ws[64 * G1S];
  int t = threadIdx.x;
  int wv = t >> 6, lane = t & 63;
  int qd = lane >> 4, md = lane & 15;
  int m0 = blockIdx.x * 64;
  f4 acc[4] = {};
  for (int ks = 0; ks < 256; ks += 128) {
    __syncthreads();
#pragma unroll
    for (int i = 0; i < 8; ++i) {               // stage x[m0..+63][ks..+127] -> bf16 LDS
      int f = t + 256 * i;                       // 2048 float4s
      int r = f >> 5, c4 = f & 31;
      int grow = m0 + r; if (grow >= N) grow = N - 1;
      float4 v = ((const float4*)x)[(size_t)grow * 64 + (ks >> 2) + c4];
      u32 p0 = (u32)f2bf(v.x) | ((u32)f2bf(v.y) << 16);
      u32 p1 = (u32)f2bf(v.z) | ((u32)f2bf(v.w) << 16);
      *((uint2*)(xs + r * G1S + c4 * 4)) = make_uint2(p0, p1);
    }
#pragma unroll
    for (int i = 0; i < 4; ++i) {               // stage W1t[0..63][ks..+127]
      int cc = t + 256 * i;                      // 1024 chunks of 8 u16
      int n = cc >> 4, kc = (cc & 15) * 8;
      *((uint4*)(ws + n * G1S + kc)) = *((const uint4*)(W1t + n * 256 + ks + kc));
    }
    __syncthreads();
#pragma unroll
    for (int kk = 0; kk < 128; kk += 32) {
      bh8 af = *((const bh8*)(xs + (16 * wv + md) * G1S + kk + qd * 8));
#pragma unroll
      for (int nt = 0; nt < 4; ++nt) {
        bh8 bf = *((const bh8*)(ws + (nt * 16 + md) * G1S + kk + qd * 8));
        acc[nt] = mfma16(af, bf, acc[nt]);
      }
    }
  }
#pragma unroll
  for (int nt = 0; nt < 4; ++nt)
#pragma unroll
    for (int r = 0; r < 4; ++r) {
      int row = m0 + 16 * wv + qd * 4 + r;
      if (row < N) h1b[(size_t)row * 64 + nt * 16 + md] = f2bf(acc[nt][r]);
    }
}

// ---------------- gemm2: h2 = bf16(hn) @ bf16(W2), MFMA ----------------
#define G2S 72
__global__ __launch_bounds__(256) void k_gemm2(const float* __restrict__ hn, const u16* __restrict__ W2t,
                                               u16* __restrict__ h2b, int N) {
  __shared__ u16 hs[64 * G2S];
  __shared__ u16 ws[128 * G2S];
  int t = threadIdx.x;
  int wv = t >> 6, lane = t & 63;
  int qd = lane >> 4, md = lane & 15;
  int m0 = blockIdx.x * 64;
#pragma unroll
  for (int i = 0; i < 4; ++i) {                 // stage hn (fp32 -> bf16)
    int f = t + 256 * i;                         // 1024 float4s
    int r = f >> 4, c4 = f & 15;
    int grow = m0 + r; if (grow >= N) grow = N - 1;
    float4 v = ((const float4*)hn)[(size_t)grow * 16 + c4];
    u32 p0 = (u32)f2bf(v.x) | ((u32)f2bf(v.y) << 16);
    u32 p1 = (u32)f2bf(v.z) | ((u32)f2bf(v.w) << 16);
    *((uint2*)(hs + r * G2S + c4 * 4)) = make_uint2(p0, p1);
  }
#pragma unroll
  for (int i = 0; i < 4; ++i) {                 // stage W2t (128x64 u16)
    int cc = t + 256 * i;
    int n = cc >> 3, kc = (cc & 7) * 8;
    *((uint4*)(ws + n * G2S + kc)) = *((const uint4*)(W2t + n * 64 + kc));
  }
  __syncthreads();
  f4 acc[8] = {};
#pragma unroll
  for (int kk = 0; kk < 64; kk += 32) {
    bh8 af = *((const bh8*)(hs + (16 * wv + md) * G2S + kk + qd * 8));
#pragma unroll
    for (int nt = 0; nt < 8; ++nt) {
      bh8 bf = *((const bh8*)(ws + (nt * 16 + md) * G2S + kk + qd * 8));
      acc[nt] = mfma16(af, bf, acc[nt]);
    }
  }
#pragma unroll
  for (int nt = 0; nt < 8; ++nt)
#pragma unroll
    for (int r = 0; r < 4; ++r) {
      int row = m0 + 16 * wv + qd * 4 + r;
      if (row < N) h2b[(size_t)row * 128 + nt * 16 + md] = f2bf(acc[nt][r]);
    }
}

// ---------------- conv1: aggregate + bias + relu + L2 normalize ----------------
__global__ __launch_bounds__(256) void k_conv1(const int* __restrict__ ptr, const u32* __restrict__ entries,
                                               const float* __restrict__ dinv1, const u32* __restrict__ h1u,
                                               const float* __restrict__ b1, float* __restrict__ hn, int N) {
  int wid = (blockIdx.x * 256 + threadIdx.x) >> 6;
  if (wid >= N) return;
  int lane = threadIdx.x & 63;
  int lp = lane & 31, hf = lane >> 5;
  int beg = ptr[wid], end = ptr[wid + 1];
  float a0 = 0.f, a1 = 0.f;
  for (int cb = beg; cb < end; cb += 64) {
    int idx = cb + lane;
    float wgt = 0.f; int s = 0;
    if (idx < end) {
      u32 e = entries[idx];
      s = (int)(e & 0xFFFFu);
      if (e & (1u << 30)) wgt = dinv1[s];
    }
    int half = (min(64, end - cb) + 1) >> 1;
    for (int i = 0; i < half; ++i) {
      int j = 2 * i + hf;
      float w = __shfl(wgt, j, 64);
      int sj  = __shfl(s, j, 64);
      u32 u = h1u[(size_t)sj * 32 + lp];
      a0 = fmaf(w, __uint_as_float(u << 16), a0);
      a1 = fmaf(w, __uint_as_float(u & 0xFFFF0000u), a1);
    }
  }
  a0 += __shfl_xor(a0, 32, 64);
  a1 += __shfl_xor(a1, 32, 64);
  float dv = dinv1[wid];
  u32 uo = h1u[(size_t)wid * 32 + lp];
  a0 = fmaf(dv, __uint_as_float(uo << 16), a0);
  a1 = fmaf(dv, __uint_as_float(uo & 0xFFFF0000u), a1);
  float2 bb = ((const float2*)b1)[lp];
  float o0 = fmaxf(fmaf(dv, a0, bb.x), 0.f);
  float o1 = fmaxf(fmaf(dv, a1, bb.y), 0.f);
  float ss = fmaf(o0, o0, o1 * o1);
#pragma unroll
  for (int off = 16; off > 0; off >>= 1) ss += __shfl_xor(ss, off, 32);
  float scale = 1.f / fmaxf(sqrtf(ss), 1e-12f);
  if (lane < 32) ((float2*)hn)[(size_t)wid * 32 + lp] = make_float2(o0 * scale, o1 * scale);
}

// ---------------- conv2: aggregate + bias -> out ----------------
__global__ __launch_bounds__(256) void k_conv2(const int* __restrict__ ptr, const u32* __restrict__ entries,
                                               const float* __restrict__ dinv2, const uint2* __restrict__ h2v,
                                               const float* __restrict__ b2, float* __restrict__ out, int N) {
  int wid = (blockIdx.x * 256 + threadIdx.x) >> 6;
  if (wid >= N) return;
  int lane = threadIdx.x & 63;
  int lp = lane & 31, hf = lane >> 5;
  int beg = ptr[wid], end = ptr[wid + 1];
  float a0 = 0.f, a1 = 0.f, a2 = 0.f, a3 = 0.f;
  for (int cb = beg; cb < end; cb += 64) {
    int idx = cb + lane;
    float wgt = 0.f; int s = 0;
    if (idx < end) {
      u32 e = entries[idx];
      s = (int)(e & 0xFFFFu);
      if (e & (1u << 31)) wgt = dinv2[s];
    }
    int half = (min(64, end - cb) + 1) >> 1;
    for (int i = 0; i < half; ++i) {
      int j = 2 * i + hf;
      float w = __shfl(wgt, j, 64);
      int sj  = __shfl(s, j, 64);
      uint2 uv = h2v[(size_t)sj * 32 + lp];
      a0 = fmaf(w, __uint_as_float(uv.x << 16), a0);
      a1 = fmaf(w, __uint_as_float(uv.x & 0xFFFF0000u), a1);
      a2 = fmaf(w, __uint_as_float(uv.y << 16), a2);
      a3 = fmaf(w, __uint_as_float(uv.y & 0xFFFF0000u), a3);
    }
  }
  a0 += __shfl_xor(a0, 32, 64);
  a1 += __shfl_xor(a1, 32, 64);
  a2 += __shfl_xor(a2, 32, 64);
  a3 += __shfl_xor(a3, 32, 64);
  float dv = dinv2[wid];
  uint2 uo = h2v[(size_t)wid * 32 + lp];
  a0 = fmaf(dv, __uint_as_float(uo.x << 16), a0);
  a1 = fmaf(dv, __uint_as_float(uo.x & 0xFFFF0000u), a1);
  a2 = fmaf(dv, __uint_as_float(uo.y << 16), a2);
  a3 = fmaf(dv, __uint_as_float(uo.y & 0xFFFF0000u), a3);
  float4 bb = ((const float4*)b2)[lp];
  float4 res;
  res.x = fmaf(dv, a0, bb.x);
  res.y = fmaf(dv, a1, bb.y);
  res.z = fmaf(dv, a2, bb.z);
  res.w = fmaf(dv, a3, bb.w);
  if (lane < 32) ((float4*)out)[(size_t)wid * 32 + lp] = res;
}

// ---------------- launch ----------------
extern "C" void kernel_launch(void* const* d_in, const int* in_sizes, int n_in,
                              void* d_out, int out_size, void* d_ws, size_t ws_size,
                              hipStream_t stream) {
  const float* x  = (const float*)d_in[0];
  const int*   ei = (const int*)d_in[1];
  const float* W1 = (const float*)d_in[2];
  const float* b1 = (const float*)d_in[3];
  const float* W2 = (const float*)d_in[4];
  const float* b2 = (const float*)d_in[5];
  const int N = in_sizes[0] / 256;
  const int E = in_sizes[1] / 2;
  const int nb = (N + 511) >> 9;   // buckets (98 for N=50000; code assumes <=128)

  u32 sk1a, sk1b, sk2a, sk2b;
  tf2x32(0u, 42u, 0u, 0u, sk1a, sk1b);
  tf2x32(0u, 42u, 0u, 1u, sk2a, sk2b);

  char* p = (char*)d_ws;
  auto alloc = [&](size_t bytes) { char* r = p; p += (bytes + 255) & ~(size_t)255; return r; };
  // --- zero-init group (contiguous) ---
  int* dstCnt      = (int*)alloc(128 * 4);
  int* srcCnt      = (int*)alloc(128 * 4);
  int* hcbA        = (int*)alloc((size_t)(1 + HMAX) * 4);
  int* hcbB        = (int*)alloc((size_t)(1 + HMAX) * 4);
  char* zero_end = p;
  // --- rest ---
  unsigned char* mask = (unsigned char*)alloc((size_t)E);
  u16* h1b      = (u16*)alloc((size_t)N * 64 * 2);
  float* hn     = (float*)alloc((size_t)N * 64 * 4);
  u16* h2b      = (u16*)alloc((size_t)N * 128 * 2);
  float* dinv1  = (float*)alloc((size_t)N * 4);
  float* dinv2  = (float*)alloc((size_t)N * 4);
  int* dptr     = (int*)alloc((size_t)(N + 1) * 4);
  int* bucketBase = (int*)alloc(129 * 4);
  int* bucketCur  = (int*)alloc(128 * 4);
  u32* records  = (u32*)alloc((size_t)E * 4);
  u32* entries  = (u32*)alloc((size_t)E * 4);
  u32* srcRec   = (u32*)alloc((size_t)nb * SB_CAP * 4);
  u64* bukA     = (u64*)alloc((size_t)HMAX * MAXD * 8);
  u64* bukB     = (u64*)alloc((size_t)HMAX * MAXD * 8);
  u16* W1t      = (u16*)alloc(256 * 64 * 2);
  u16* W2t      = (u16*)alloc(64 * 128 * 2);

  int* hcA = hcbA; int* bcA = hcbA + 1;
  int* hcB = hcbB; int* bcB = hcbB + 1;

  hipMemsetAsync(dstCnt, 0x00, (size_t)(zero_end - (char*)dstCnt), stream);
  hipMemsetAsync(mask, 0x03, (size_t)E, stream);

  k_prep<<<4, 256, 0, stream>>>(W1, W2, W1t, W2t);
  k_srcbin<<<(E + SBCHUNK - 1) / SBCHUNK, 256, 0, stream>>>(ei, srcCnt, srcRec, dstCnt, E, nb);
  k_srcproc<<<nb, 256, 0, stream>>>(srcCnt, srcRec, hcA, bcA, bukA, hcB, bcB, bukB, N,
                                    sk1a, sk1b, sk2a, sk2b);
  k_scanbk<<<1, 64, 0, stream>>>(dstCnt, bucketBase, bucketCur, dptr, nb, N);
  k_rank<<<HMAX / 4, 256, 0, stream>>>(hcA, bcA, bukA, mask, 100, 0x1);
  k_rank<<<HMAX / 4, 256, 0, stream>>>(hcB, bcB, bukB, mask, 50, 0x2);
  k_phase1<<<(E + P1CHUNK - 1) / P1CHUNK, 256, 0, stream>>>(ei, mask, bucketCur, records, E);
  k_phase2<<<nb, 256, 0, stream>>>(bucketBase, records, entries, dptr, dinv1, dinv2, N);

  k_gemm1<<<(N + 63) / 64, 256, 0, stream>>>(x, W1t, h1b, N);
  k_conv1<<<(N * 64 + 255) / 256, 256, 0, stream>>>(dptr, entries, dinv1, (const u32*)h1b, b1, hn, N);
  k_gemm2<<<(N + 63) / 64, 256, 0, stream>>>(hn, W2t, h2b, N);
  k_conv2<<<(N * 64 + 255) / 256, 256, 0, stream>>>(dptr, entries, dinv2, (const uint2*)h2b, b2,
                                                    (float*)d_out, N);
}

// Round 5
// 361.413 us; speedup vs baseline: 2.3093x; 1.0996x over previous
//
#include <hip/hip_runtime.h>

typedef unsigned int u32;
typedef unsigned short u16;
typedef unsigned long long u64;
typedef __attribute__((ext_vector_type(8))) short bh8;   // 8 bf16 (4 VGPRs) MFMA frag
typedef __attribute__((ext_vector_type(4))) float f4;    // 4 fp32 acc

#define HMAX 1024   // max heavy (deg>S) nodes tracked; expected ~65
#define MAXD 128    // max out-degree bucketed; expected max ~58
#define SB_CAP 24576  // src-bin capacity: mean 16384, sigma ~127 -> +64 sigma
#define SBCHUNK 2048

__device__ inline f4 mfma16(bh8 a, bh8 b, f4 c) {
  return __builtin_amdgcn_mfma_f32_16x16x32_bf16(a, b, c, 0, 0, 0);
}

// ---------------- threefry2x32 (exact JAX cipher) ----------------
__host__ __device__ inline void tf2x32(u32 k0, u32 k1, u32 x0, u32 x1, u32& o0, u32& o1) {
  u32 ks2 = k0 ^ k1 ^ 0x1BD11BDAu;
#define ROTL32(x,d) (((x)<<(d))|((x)>>(32-(d))))
#define TFR(r) { x0 += x1; x1 = ROTL32(x1,(r)); x1 ^= x0; }
  x0 += k0; x1 += k1;
  TFR(13) TFR(15) TFR(26) TFR(6)
  x0 += k1; x1 += ks2 + 1u;
  TFR(17) TFR(29) TFR(16) TFR(24)
  x0 += ks2; x1 += k0 + 2u;
  TFR(13) TFR(15) TFR(26) TFR(6)
  x0 += k0; x1 += k1 + 3u;
  TFR(17) TFR(29) TFR(16) TFR(24)
  x0 += k1; x1 += ks2 + 4u;
  TFR(13) TFR(15) TFR(26) TFR(6)
  x0 += ks2; x1 += k0 + 5u;
  o0 = x0; o1 = x1;
#undef TFR
#undef ROTL32
}

__device__ inline u16 f2bf(float f) {      // round-to-nearest-even (finite inputs)
  u32 u = __float_as_uint(f);
  return (u16)((u + 0x7FFFu + ((u >> 16) & 1u)) >> 16);
}

// ---------------- weight pre-transpose to bf16 n-major ----------------
__global__ __launch_bounds__(256) void k_prep(const float* __restrict__ W1, const float* __restrict__ W2,
                                              u16* __restrict__ W1t, u16* __restrict__ W2t) {
  int t = blockIdx.x * 256 + threadIdx.x;   // grid 4 x 256
  for (int e = t; e < 256 * 64; e += 1024) {
    int n = e & 63, k = e >> 6;
    W1t[n * 256 + k] = f2bf(W1[k * 64 + n]);
  }
  for (int e = t; e < 64 * 128; e += 1024) {
    int n = e & 127, k = e >> 7;
    W2t[n * 64 + k] = f2bf(W2[k * 128 + n]);
  }
}

// ---------------- src-binned record scatter + dst-bucket histogram ----------------
// src record = srclow9 (21:29) | edgeid (0:20)
__global__ __launch_bounds__(256) void k_srcbin(const int* __restrict__ ei,
                                                int* __restrict__ srcCnt, u32* __restrict__ srcRec,
                                                int* __restrict__ dstCnt, int E, int nb) {
  __shared__ u32 lsrc[128], ldst[128], lbase[128];
  int t = threadIdx.x;
  if (t < 128) { lsrc[t] = 0; ldst[t] = 0; }
  __syncthreads();
  int lo = blockIdx.x * SBCHUNK;
  int hi = min(lo + SBCHUNK, E);
  int sv[SBCHUNK / 256];
  int ci = 0;
  for (int i = lo + t; i < hi; i += 256) {
    int s = ei[i];
    int d = ei[E + i];
    sv[ci++] = s;
    atomicAdd(&lsrc[s >> 9], 1u);
    atomicAdd(&ldst[d >> 9], 1u);
  }
  __syncthreads();
  if (t < 128) {
    u32 c = lsrc[t];
    if (c) lbase[t] = (u32)atomicAdd(&srcCnt[t], (int)c);
    lsrc[t] = 0;
    if (ldst[t]) atomicAdd(&dstCnt[t], (int)ldst[t]);
  }
  __syncthreads();
  ci = 0;
  for (int i = lo + t; i < hi; i += 256) {
    int s = sv[ci++];
    int bk = s >> 9;
    u32 slot = lbase[bk] + atomicAdd(&lsrc[bk], 1u);
    if (slot < SB_CAP)
      srcRec[(size_t)bk * SB_CAP + slot] = ((u32)(s & 511) << 21) | (u32)i;
  }
}

// ---------------- per-src-bucket: out-degree count + heavy detect + PRNG bucketing ----------------
__global__ __launch_bounds__(256) void k_srcproc(const int* __restrict__ srcCnt, const u32* __restrict__ srcRec,
                                                 int* __restrict__ hcA, int* __restrict__ bcA, u64* __restrict__ bukA,
                                                 int* __restrict__ hcB, int* __restrict__ bcB, u64* __restrict__ bukB,
                                                 int N, u32 kaA, u32 kbA, u32 kaB, u32 kbB) {
  int bk = blockIdx.x;
  int cnt0 = min(srcCnt[bk], SB_CAP);
  __shared__ u32 cnt[512];
  __shared__ int idA[512], idB[512];
  int t = threadIdx.x;
  cnt[t] = 0; cnt[t + 256] = 0;
  __syncthreads();
  const u32* R = srcRec + (size_t)bk * SB_CAP;
  for (int i = t; i < cnt0; i += 256) atomicAdd(&cnt[R[i] >> 21], 1u);
  __syncthreads();
  for (int v = t; v < 512; v += 256) {
    idA[v] = -1; idB[v] = -1;
    int node = bk * 512 + v;
    if (node < N) {
      u32 dg = cnt[v];
      if (dg > 100u) { int id = atomicAdd(hcA, 1); if (id < HMAX) idA[v] = id; }
      if (dg > 50u)  { int id = atomicAdd(hcB, 1); if (id < HMAX) idB[v] = id; }
    }
  }
  __syncthreads();
  for (int i = t; i < cnt0; i += 256) {
    u32 r = R[i];
    int sl = (int)(r >> 21);
    u32 e = r & 0x1FFFFFu;
    int ib = idB[sl];
    if (ib >= 0) {
      u32 w0, w1; tf2x32(kaB, kbB, 0u, e, w0, w1);
      u32 key = (w0 ^ w1) >> 9;
      int slot = atomicAdd(&bcB[ib], 1);
      if (slot < MAXD) bukB[(size_t)ib * MAXD + slot] = ((u64)key << 32) | e;
      int ia = idA[sl];
      if (ia >= 0) {
        tf2x32(kaA, kbA, 0u, e, w0, w1);
        key = (w0 ^ w1) >> 9;
        slot = atomicAdd(&bcA[ia], 1);
        if (slot < MAXD) bukA[(size_t)ia * MAXD + slot] = ((u64)key << 32) | e;
      }
    }
  }
}

// ---------------- tiny scan: dstCnt -> bucketBase / bucketCur ----------------
__global__ void k_scanbk(const int* __restrict__ bucketCount, int* __restrict__ bucketBase,
                         int* __restrict__ bucketCur, int* __restrict__ dptr, int nb, int N) {
  if (threadIdx.x == 0) {
    int s = 0;
    for (int i = 0; i < nb; ++i) { bucketBase[i] = s; bucketCur[i] = s; s += bucketCount[i]; }
    bucketBase[nb] = s;
    dptr[N] = s;   // == E
  }
}

// rank each bucketed edge by (key, idx); drop rank >= S  (clears `bit` in mask)
__global__ __launch_bounds__(256) void k_rank(const int* __restrict__ hcount, const int* __restrict__ bcount,
                                              const u64* __restrict__ bucket, unsigned char* __restrict__ mask,
                                              int S, int bit) {
  int wid = (blockIdx.x * 256 + threadIdx.x) >> 6;
  int lane = threadIdx.x & 63;
  int hc = hcount[0]; if (hc > HMAX) hc = HMAX;
  if (wid >= hc) return;
  int d = bcount[wid]; if (d > MAXD) d = MAXD;
  const u64* B = bucket + (size_t)wid * MAXD;
  for (int i = lane; i < d; i += 64) {
    u64 ki = B[i];
    int rank = 0;
    for (int j = 0; j < d; ++j) rank += (B[j] < ki) ? 1 : 0;
    if (rank >= S) {
      u32 e = (u32)ki;
      mask[e] = (unsigned char)(mask[e] & ~bit);
    }
  }
}

// ---------------- phase 1: binned scatter of edge records ----------------
// record = src(0:15) | dstlow(16:24) | m1(25) | m2(26)
#define P1CHUNK 8192
__global__ __launch_bounds__(256) void k_phase1(const int* __restrict__ ei,
                                                const unsigned char* __restrict__ mask,
                                                int* __restrict__ bucketCur, u32* __restrict__ records, int E) {
  __shared__ u32 lc[128];
  __shared__ u32 lbase[128];
  int t = threadIdx.x;
  if (t < 128) lc[t] = 0;
  __syncthreads();
  int lo = blockIdx.x * P1CHUNK;
  int hi = min(lo + P1CHUNK, E);
  for (int i = lo + t; i < hi; i += 256) {
    int d = ei[E + i];
    atomicAdd(&lc[d >> 9], 1u);
  }
  __syncthreads();
  if (t < 128) {
    u32 c = lc[t];
    if (c) lbase[t] = (u32)atomicAdd(&bucketCur[t], (int)c);
    lc[t] = 0;
  }
  __syncthreads();
  for (int i = lo + t; i < hi; i += 256) {
    int s = ei[i];
    int d = ei[E + i];
    unsigned char m = mask[i];
    int bk = d >> 9;
    u32 slot = lbase[bk] + atomicAdd(&lc[bk], 1u);
    records[slot] = (u32)s | ((u32)(d & 511) << 16) | ((u32)(m & 3u) << 25);
  }
}

// ---------------- phase 2: per-bucket counting sort -> entries/dptr/dinv ----------------
__global__ __launch_bounds__(256) void k_phase2(const int* __restrict__ bucketBase,
                                                const u32* __restrict__ records,
                                                u32* __restrict__ entries, int* __restrict__ dptr,
                                                float* __restrict__ dinv1, float* __restrict__ dinv2, int N) {
  int b = blockIdx.x;
  int lo = bucketBase[b], hi = bucketBase[b + 1];
  __shared__ u32 cnt[512];
  __shared__ u32 ws4[4];
  int t = threadIdx.x;
  cnt[t] = 0; cnt[t + 256] = 0;
  __syncthreads();
  for (int i = lo + t; i < hi; i += 256) {
    u32 r = records[i];
    u32 dl = (r >> 16) & 511u;
    u32 add = 1u + (((r >> 25) & 1u) << 10) + (((r >> 26) & 1u) << 20);
    atomicAdd(&cnt[dl], add);
  }
  __syncthreads();
  u32 c0 = cnt[2 * t], c1 = cnt[2 * t + 1];
  u32 n0 = c0 & 1023u, n1 = c1 & 1023u;
  u32 pair = n0 + n1;
  int lane = t & 63, w = t >> 6;
  u32 incl = pair;
  for (int off = 1; off < 64; off <<= 1) {
    u32 nbv = (u32)__shfl_up((int)incl, off, 64);
    if (lane >= off) incl += nbv;
  }
  if (lane == 63) ws4[w] = incl;
  __syncthreads();
  if (t == 0) { u32 s = 0; for (int k = 0; k < 4; ++k) { u32 x = ws4[k]; ws4[k] = s; s += x; } }
  __syncthreads();
  u32 excl = incl - pair + ws4[w];
  int v0 = b * 512 + 2 * t;
  if (v0 < N) {
    dptr[v0] = lo + (int)excl;
    dinv1[v0] = 1.0f / sqrtf((float)(((c0 >> 10) & 1023u) + 1u));
    dinv2[v0] = 1.0f / sqrtf((float)(((c0 >> 20) & 1023u) + 1u));
  }
  if (v0 + 1 < N) {
    dptr[v0 + 1] = lo + (int)(excl + n0);
    dinv1[v0 + 1] = 1.0f / sqrtf((float)(((c1 >> 10) & 1023u) + 1u));
    dinv2[v0 + 1] = 1.0f / sqrtf((float)(((c1 >> 20) & 1023u) + 1u));
  }
  __syncthreads();
  cnt[2 * t] = excl;
  cnt[2 * t + 1] = excl + n0;
  __syncthreads();
  for (int i = lo + t; i < hi; i += 256) {
    u32 r = records[i];
    u32 dl = (r >> 16) & 511u;
    u32 slot = atomicAdd(&cnt[dl], 1u);
    entries[lo + slot] = (r & 0xFFFFu) | ((r & (1u << 25)) ? (1u << 30) : 0u)
                                       | ((r & (1u << 26)) ? (1u << 31) : 0u);
  }
}

// ---------------- gemm1: h1 = bf16(x) @ bf16(W1), MFMA 16x16x32, K-split staging ----------------
#define G1S 136   // LDS row stride (128 + 8 pad) -> 2-way bank alias only (free)
__global__ __launch_bounds__(256) void k_gemm1(const float* __restrict__ x, const u16* __restrict__ W1t,
                                               u16* __restrict__ h1b, int N) {
  __shared__ u16 xs[64 * G1S];
  __shared__ u16 ws[64 * G1S];
  int t = threadIdx.x;
  int wv = t >> 6, lane = t & 63;
  int qd = lane >> 4, md = lane & 15;
  int m0 = blockIdx.x * 64;
  f4 acc[4] = {};
  for (int ks = 0; ks < 256; ks += 128) {
    __syncthreads();
#pragma unroll
    for (int i = 0; i < 8; ++i) {               // stage x[m0..+63][ks..+127] -> bf16 LDS
      int f = t + 256 * i;                       // 2048 float4s
      int r = f >> 5, c4 = f & 31;
      int grow = m0 + r; if (grow >= N) grow = N - 1;
      float4 v = ((const float4*)x)[(size_t)grow * 64 + (ks >> 2) + c4];
      u32 p0 = (u32)f2bf(v.x) | ((u32)f2bf(v.y) << 16);
      u32 p1 = (u32)f2bf(v.z) | ((u32)f2bf(v.w) << 16);
      *((uint2*)(xs + r * G1S + c4 * 4)) = make_uint2(p0, p1);
    }
#pragma unroll
    for (int i = 0; i < 4; ++i) {               // stage W1t[0..63][ks..+127]
      int cc = t + 256 * i;                      // 1024 chunks of 8 u16
      int n = cc >> 4, kc = (cc & 15) * 8;
      *((uint4*)(ws + n * G1S + kc)) = *((const uint4*)(W1t + n * 256 + ks + kc));
    }
    __syncthreads();
#pragma unroll
    for (int kk = 0; kk < 128; kk += 32) {
      bh8 af = *((const bh8*)(xs + (16 * wv + md) * G1S + kk + qd * 8));
#pragma unroll
      for (int nt = 0; nt < 4; ++nt) {
        bh8 bf = *((const bh8*)(ws + (nt * 16 + md) * G1S + kk + qd * 8));
        acc[nt] = mfma16(af, bf, acc[nt]);
      }
    }
  }
#pragma unroll
  for (int nt = 0; nt < 4; ++nt)
#pragma unroll
    for (int r = 0; r < 4; ++r) {
      int row = m0 + 16 * wv + qd * 4 + r;
      if (row < N) h1b[(size_t)row * 64 + nt * 16 + md] = f2bf(acc[nt][r]);
    }
}

// ---------------- conv1: aggregate h1 + bias + relu + L2 normalize -> bf16 hnb ----------------
// wave per dst; quarter-wave: 16 lanes x uint2(8B) = 128B row, 4 src rows in flight
__global__ __launch_bounds__(256) void k_conv1n(const int* __restrict__ ptr, const u32* __restrict__ entries,
                                                const float* __restrict__ dinv1, const uint2* __restrict__ h1v,
                                                const float* __restrict__ b1, uint2* __restrict__ hnb, int N) {
  int wid = (blockIdx.x * 256 + threadIdx.x) >> 6;
  if (wid >= N) return;
  int lane = threadIdx.x & 63;
  int lq = lane & 15, qw = lane >> 4;
  int beg = ptr[wid], end = ptr[wid + 1];
  float a0 = 0.f, a1 = 0.f, a2 = 0.f, a3 = 0.f;
  for (int cb = beg; cb < end; cb += 64) {
    int idx = cb + lane;
    float wgt = 0.f; int s = 0;
    if (idx < end) {
      u32 e = entries[idx];
      s = (int)(e & 0xFFFFu);
      if (e & (1u << 30)) wgt = dinv1[s];
    }
    int nq = (min(64, end - cb) + 3) >> 2;
    for (int i = 0; i < nq; ++i) {
      int j = 4 * i + qw;
      float w = __shfl(wgt, j, 64);
      int sj  = __shfl(s, j, 64);
      uint2 uv = h1v[(size_t)sj * 16 + lq];
      a0 = fmaf(w, __uint_as_float(uv.x << 16), a0);
      a1 = fmaf(w, __uint_as_float(uv.x & 0xFFFF0000u), a1);
      a2 = fmaf(w, __uint_as_float(uv.y << 16), a2);
      a3 = fmaf(w, __uint_as_float(uv.y & 0xFFFF0000u), a3);
    }
  }
  a0 += __shfl_xor(a0, 16, 64); a0 += __shfl_xor(a0, 32, 64);
  a1 += __shfl_xor(a1, 16, 64); a1 += __shfl_xor(a1, 32, 64);
  a2 += __shfl_xor(a2, 16, 64); a2 += __shfl_xor(a2, 32, 64);
  a3 += __shfl_xor(a3, 16, 64); a3 += __shfl_xor(a3, 32, 64);
  float dv = dinv1[wid];
  uint2 uo = h1v[(size_t)wid * 16 + lq];
  a0 = fmaf(dv, __uint_as_float(uo.x << 16), a0);
  a1 = fmaf(dv, __uint_as_float(uo.x & 0xFFFF0000u), a1);
  a2 = fmaf(dv, __uint_as_float(uo.y << 16), a2);
  a3 = fmaf(dv, __uint_as_float(uo.y & 0xFFFF0000u), a3);
  float4 bb = ((const float4*)b1)[lq];
  float o0 = fmaxf(fmaf(dv, a0, bb.x), 0.f);
  float o1 = fmaxf(fmaf(dv, a1, bb.y), 0.f);
  float o2 = fmaxf(fmaf(dv, a2, bb.z), 0.f);
  float o3 = fmaxf(fmaf(dv, a3, bb.w), 0.f);
  float ss = fmaf(o0, o0, fmaf(o1, o1, fmaf(o2, o2, o3 * o3)));
#pragma unroll
  for (int off = 8; off > 0; off >>= 1) ss += __shfl_xor(ss, off, 16);
  float sc = 1.f / fmaxf(sqrtf(ss), 1e-12f);
  if (lane < 16) {
    u32 p0 = (u32)f2bf(o0 * sc) | ((u32)f2bf(o1 * sc) << 16);
    u32 p1 = (u32)f2bf(o2 * sc) | ((u32)f2bf(o3 * sc) << 16);
    hnb[(size_t)wid * 16 + lq] = make_uint2(p0, p1);
  }
}

// ---------------- agg2: aggregate hnb with dinv2 -> bf16 agg2b (gemm moved after) ----------------
__global__ __launch_bounds__(256) void k_agg2(const int* __restrict__ ptr, const u32* __restrict__ entries,
                                              const float* __restrict__ dinv2, const uint2* __restrict__ hnv,
                                              uint2* __restrict__ agg2b, int N) {
  int wid = (blockIdx.x * 256 + threadIdx.x) >> 6;
  if (wid >= N) return;
  int lane = threadIdx.x & 63;
  int lq = lane & 15, qw = lane >> 4;
  int beg = ptr[wid], end = ptr[wid + 1];
  float a0 = 0.f, a1 = 0.f, a2 = 0.f, a3 = 0.f;
  for (int cb = beg; cb < end; cb += 64) {
    int idx = cb + lane;
    float wgt = 0.f; int s = 0;
    if (idx < end) {
      u32 e = entries[idx];
      s = (int)(e & 0xFFFFu);
      if (e & (1u << 31)) wgt = dinv2[s];
    }
    int nq = (min(64, end - cb) + 3) >> 2;
    for (int i = 0; i < nq; ++i) {
      int j = 4 * i + qw;
      float w = __shfl(wgt, j, 64);
      int sj  = __shfl(s, j, 64);
      uint2 uv = hnv[(size_t)sj * 16 + lq];
      a0 = fmaf(w, __uint_as_float(uv.x << 16), a0);
      a1 = fmaf(w, __uint_as_float(uv.x & 0xFFFF0000u), a1);
      a2 = fmaf(w, __uint_as_float(uv.y << 16), a2);
      a3 = fmaf(w, __uint_as_float(uv.y & 0xFFFF0000u), a3);
    }
  }
  a0 += __shfl_xor(a0, 16, 64); a0 += __shfl_xor(a0, 32, 64);
  a1 += __shfl_xor(a1, 16, 64); a1 += __shfl_xor(a1, 32, 64);
  a2 += __shfl_xor(a2, 16, 64); a2 += __shfl_xor(a2, 32, 64);
  a3 += __shfl_xor(a3, 16, 64); a3 += __shfl_xor(a3, 32, 64);
  float dv = dinv2[wid];
  uint2 uo = hnv[(size_t)wid * 16 + lq];
  a0 = fmaf(dv, __uint_as_float(uo.x << 16), a0);
  a1 = fmaf(dv, __uint_as_float(uo.x & 0xFFFF0000u), a1);
  a2 = fmaf(dv, __uint_as_float(uo.y << 16), a2);
  a3 = fmaf(dv, __uint_as_float(uo.y & 0xFFFF0000u), a3);
  if (lane < 16) {
    u32 p0 = (u32)f2bf(dv * a0) | ((u32)f2bf(dv * a1) << 16);
    u32 p1 = (u32)f2bf(dv * a2) | ((u32)f2bf(dv * a3) << 16);
    agg2b[(size_t)wid * 16 + lq] = make_uint2(p0, p1);
  }
}

// ---------------- gemm2f: out = agg2b @ W2 + b2 (MFMA, fused bias, fp32 out) ----------------
#define G2S 72
__global__ __launch_bounds__(256) void k_gemm2f(const u16* __restrict__ aggb, const u16* __restrict__ W2t,
                                                const float* __restrict__ b2, float* __restrict__ out, int N) {
  __shared__ u16 hs[64 * G2S];
  __shared__ u16 ws[128 * G2S];
  int t = threadIdx.x;
  int wv = t >> 6, lane = t & 63;
  int qd = lane >> 4, md = lane & 15;
  int m0 = blockIdx.x * 64;
#pragma unroll
  for (int i = 0; i < 2; ++i) {                 // stage aggb: 64 rows x 64 u16 = 512 uint4
    int cc = t + 256 * i;
    int r = cc >> 3, kc = (cc & 7) * 8;
    int grow = m0 + r; if (grow >= N) grow = N - 1;
    *((uint4*)(hs + r * G2S + kc)) = *((const uint4*)(aggb + (size_t)grow * 64 + kc));
  }
#pragma unroll
  for (int i = 0; i < 4; ++i) {                 // stage W2t (128x64 u16)
    int cc = t + 256 * i;
    int n = cc >> 3, kc = (cc & 7) * 8;
    *((uint4*)(ws + n * G2S + kc)) = *((const uint4*)(W2t + n * 64 + kc));
  }
  __syncthreads();
  f4 acc[8] = {};
#pragma unroll
  for (int kk = 0; kk < 64; kk += 32) {
    bh8 af = *((const bh8*)(hs + (16 * wv + md) * G2S + kk + qd * 8));
#pragma unroll
    for (int nt = 0; nt < 8; ++nt) {
      bh8 bf = *((const bh8*)(ws + (nt * 16 + md) * G2S + kk + qd * 8));
      acc[nt] = mfma16(af, bf, acc[nt]);
    }
  }
#pragma unroll
  for (int nt = 0; nt < 8; ++nt) {
    float bv = b2[nt * 16 + md];
#pragma unroll
    for (int r = 0; r < 4; ++r) {
      int row = m0 + 16 * wv + qd * 4 + r;
      if (row < N) out[(size_t)row * 128 + nt * 16 + md] = acc[nt][r] + bv;
    }
  }
}

// ---------------- launch ----------------
extern "C" void kernel_launch(void* const* d_in, const int* in_sizes, int n_in,
                              void* d_out, int out_size, void* d_ws, size_t ws_size,
                              hipStream_t stream) {
  const float* x  = (const float*)d_in[0];
  const int*   ei = (const int*)d_in[1];
  const float* W1 = (const float*)d_in[2];
  const float* b1 = (const float*)d_in[3];
  const float* W2 = (const float*)d_in[4];
  const float* b2 = (const float*)d_in[5];
  const int N = in_sizes[0] / 256;
  const int E = in_sizes[1] / 2;
  const int nb = (N + 511) >> 9;   // buckets (98 for N=50000; code assumes <=128)

  u32 sk1a, sk1b, sk2a, sk2b;
  tf2x32(0u, 42u, 0u, 0u, sk1a, sk1b);
  tf2x32(0u, 42u, 0u, 1u, sk2a, sk2b);

  char* p = (char*)d_ws;
  auto alloc = [&](size_t bytes) { char* r = p; p += (bytes + 255) & ~(size_t)255; return r; };
  // --- zero-init group (contiguous) ---
  int* dstCnt      = (int*)alloc(128 * 4);
  int* srcCnt      = (int*)alloc(128 * 4);
  int* hcbA        = (int*)alloc((size_t)(1 + HMAX) * 4);
  int* hcbB        = (int*)alloc((size_t)(1 + HMAX) * 4);
  char* zero_end = p;
  // --- rest ---
  unsigned char* mask = (unsigned char*)alloc((size_t)E);
  u16* h1b      = (u16*)alloc((size_t)N * 64 * 2);
  u16* hnb      = (u16*)alloc((size_t)N * 64 * 2);
  u16* agg2b    = (u16*)alloc((size_t)N * 64 * 2);
  float* dinv1  = (float*)alloc((size_t)N * 4);
  float* dinv2  = (float*)alloc((size_t)N * 4);
  int* dptr     = (int*)alloc((size_t)(N + 1) * 4);
  int* bucketBase = (int*)alloc(129 * 4);
  int* bucketCur  = (int*)alloc(128 * 4);
  u32* records  = (u32*)alloc((size_t)E * 4);
  u32* entries  = (u32*)alloc((size_t)E * 4);
  u32* srcRec   = (u32*)alloc((size_t)nb * SB_CAP * 4);
  u64* bukA     = (u64*)alloc((size_t)HMAX * MAXD * 8);
  u64* bukB     = (u64*)alloc((size_t)HMAX * MAXD * 8);
  u16* W1t      = (u16*)alloc(256 * 64 * 2);
  u16* W2t      = (u16*)alloc(64 * 128 * 2);

  int* hcA = hcbA; int* bcA = hcbA + 1;
  int* hcB = hcbB; int* bcB = hcbB + 1;

  hipMemsetAsync(dstCnt, 0x00, (size_t)(zero_end - (char*)dstCnt), stream);
  hipMemsetAsync(mask, 0x03, (size_t)E, stream);

  k_prep<<<4, 256, 0, stream>>>(W1, W2, W1t, W2t);
  k_srcbin<<<(E + SBCHUNK - 1) / SBCHUNK, 256, 0, stream>>>(ei, srcCnt, srcRec, dstCnt, E, nb);
  k_srcproc<<<nb, 256, 0, stream>>>(srcCnt, srcRec, hcA, bcA, bukA, hcB, bcB, bukB, N,
                                    sk1a, sk1b, sk2a, sk2b);
  k_scanbk<<<1, 64, 0, stream>>>(dstCnt, bucketBase, bucketCur, dptr, nb, N);
  k_rank<<<HMAX / 4, 256, 0, stream>>>(hcA, bcA, bukA, mask, 100, 0x1);
  k_rank<<<HMAX / 4, 256, 0, stream>>>(hcB, bcB, bukB, mask, 50, 0x2);
  k_phase1<<<(E + P1CHUNK - 1) / P1CHUNK, 256, 0, stream>>>(ei, mask, bucketCur, records, E);
  k_phase2<<<nb, 256, 0, stream>>>(bucketBase, records, entries, dptr, dinv1, dinv2, N);

  k_gemm1<<<(N + 63) / 64, 256, 0, stream>>>(x, W1t, h1b, N);
  k_conv1n<<<(N * 64 + 255) / 256, 256, 0, stream>>>(dptr, entries, dinv1, (const uint2*)h1b, b1,
                                                     (uint2*)hnb, N);
  k_agg2<<<(N * 64 + 255) / 256, 256, 0, stream>>>(dptr, entries, dinv2, (const uint2*)hnb,
                                                   (uint2*)agg2b, N);
  k_gemm2f<<<(N + 63) / 64, 256, 0, stream>>>(agg2b, W2t, b2, (float*)d_out, N);
}

// Round 6
// 333.463 us; speedup vs baseline: 2.5029x; 1.0838x over previous
//
#include <hip/hip_runtime.h>

typedef unsigned int u32;
typedef unsigned short u16;
typedef unsigned long long u64;
typedef __attribute__((ext_vector_type(8))) short bh8;   // 8 bf16 (4 VGPRs) MFMA frag
typedef __attribute__((ext_vector_type(4))) float f4;    // 4 fp32 acc

#define HMAX 1024   // max heavy (deg>S) nodes tracked; expected ~65
#define MAXD 128    // max out-degree bucketed; expected max ~58
#define SB_CAP 24576  // src-bin capacity: mean 16384, sigma ~127 -> +64 sigma
#define SBCHUNK 2048
#define SPLIT 8     // blocks per src bucket in shist/hfill

__device__ inline f4 mfma16(bh8 a, bh8 b, f4 c) {
  return __builtin_amdgcn_mfma_f32_16x16x32_bf16(a, b, c, 0, 0, 0);
}

// ---------------- threefry2x32 (exact JAX cipher) ----------------
__host__ __device__ inline void tf2x32(u32 k0, u32 k1, u32 x0, u32 x1, u32& o0, u32& o1) {
  u32 ks2 = k0 ^ k1 ^ 0x1BD11BDAu;
#define ROTL32(x,d) (((x)<<(d))|((x)>>(32-(d))))
#define TFR(r) { x0 += x1; x1 = ROTL32(x1,(r)); x1 ^= x0; }
  x0 += k0; x1 += k1;
  TFR(13) TFR(15) TFR(26) TFR(6)
  x0 += k1; x1 += ks2 + 1u;
  TFR(17) TFR(29) TFR(16) TFR(24)
  x0 += ks2; x1 += k0 + 2u;
  TFR(13) TFR(15) TFR(26) TFR(6)
  x0 += k0; x1 += k1 + 3u;
  TFR(17) TFR(29) TFR(16) TFR(24)
  x0 += k1; x1 += ks2 + 4u;
  TFR(13) TFR(15) TFR(26) TFR(6)
  x0 += ks2; x1 += k0 + 5u;
  o0 = x0; o1 = x1;
#undef TFR
#undef ROTL32
}

__device__ inline u16 f2bf(float f) {      // round-to-nearest-even (finite inputs)
  u32 u = __float_as_uint(f);
  return (u16)((u + 0x7FFFu + ((u >> 16) & 1u)) >> 16);
}

// ---------------- weight pre-transpose to bf16 n-major ----------------
__global__ __launch_bounds__(256) void k_prep(const float* __restrict__ W1, const float* __restrict__ W2,
                                              u16* __restrict__ W1t, u16* __restrict__ W2t) {
  int t = blockIdx.x * 256 + threadIdx.x;   // grid 4 x 256
  for (int e = t; e < 256 * 64; e += 1024) {
    int n = e & 63, k = e >> 6;
    W1t[n * 256 + k] = f2bf(W1[k * 64 + n]);
  }
  for (int e = t; e < 64 * 128; e += 1024) {
    int n = e & 127, k = e >> 7;
    W2t[n * 64 + k] = f2bf(W2[k * 128 + n]);
  }
}

// ---------------- src-binned record scatter + dst-bucket histogram ----------------
// src record = srclow9 (21:29) | edgeid (0:20)
__global__ __launch_bounds__(256) void k_srcbin(const int* __restrict__ ei,
                                                int* __restrict__ srcCnt, u32* __restrict__ srcRec,
                                                int* __restrict__ dstCnt, int E, int nb) {
  __shared__ u32 lsrc[128], ldst[128], lbase[128];
  int t = threadIdx.x;
  if (t < 128) { lsrc[t] = 0; ldst[t] = 0; }
  __syncthreads();
  int lo = blockIdx.x * SBCHUNK;
  int hi = min(lo + SBCHUNK, E);
  int sv[SBCHUNK / 256];
  int ci = 0;
  for (int i = lo + t; i < hi; i += 256) {
    int s = ei[i];
    int d = ei[E + i];
    sv[ci++] = s;
    atomicAdd(&lsrc[s >> 9], 1u);
    atomicAdd(&ldst[d >> 9], 1u);
  }
  __syncthreads();
  if (t < 128) {
    u32 c = lsrc[t];
    if (c) lbase[t] = (u32)atomicAdd(&srcCnt[t], (int)c);
    lsrc[t] = 0;
    if (ldst[t]) atomicAdd(&dstCnt[t], (int)ldst[t]);
  }
  __syncthreads();
  ci = 0;
  for (int i = lo + t; i < hi; i += 256) {
    int s = sv[ci++];
    int bk = s >> 9;
    u32 slot = lbase[bk] + atomicAdd(&lsrc[bk], 1u);
    if (slot < SB_CAP)
      srcRec[(size_t)bk * SB_CAP + slot] = ((u32)(s & 511) << 21) | (u32)i;
  }
}

// ---------------- shist: partial LDS histograms -> global outdegB ----------------
__global__ __launch_bounds__(256) void k_shist(const int* __restrict__ srcCnt, const u32* __restrict__ srcRec,
                                               int* __restrict__ outdegB) {
  int bk = blockIdx.x >> 3;          // / SPLIT
  int part = blockIdx.x & (SPLIT - 1);
  int total = min(srcCnt[bk], SB_CAP);
  int lo = total * part / SPLIT;
  int hi = total * (part + 1) / SPLIT;
  __shared__ u32 cnt[512];
  int t = threadIdx.x;
  cnt[t] = 0; cnt[t + 256] = 0;
  __syncthreads();
  const u32* R = srcRec + (size_t)bk * SB_CAP;
  for (int i = lo + t; i < hi; i += 256) atomicAdd(&cnt[R[i] >> 21], 1u);
  __syncthreads();
  int base = bk * 512;
  for (int v = t; v < 512; v += 256) {
    u32 c = cnt[v];
    if (c) atomicAdd(&outdegB[base + v], (int)c);
  }
}

// ---------------- hdetect: heavy-id assignment (+ folded dst-bucket scan) ----------------
__global__ __launch_bounds__(256) void k_hdetect(const int* __restrict__ outdegB, u32* __restrict__ idAB,
                                                 int* __restrict__ hcA, int* __restrict__ hcB,
                                                 const int* __restrict__ dstCnt, int* __restrict__ bucketBase,
                                                 int* __restrict__ bucketCur, int* __restrict__ dptr,
                                                 int nb, int N) {
  if (blockIdx.x == 0 && threadIdx.x == 0) {
    int s = 0;
    for (int i = 0; i < nb; ++i) { bucketBase[i] = s; bucketCur[i] = s; s += dstCnt[i]; }
    bucketBase[nb] = s;
    dptr[N] = s;   // == E
  }
  int v = blockIdx.x * 256 + threadIdx.x;
  if (v >= N) return;
  int dg = outdegB[v];
  u32 pk = 0;
  if (dg > 50) {
    int idb = atomicAdd(hcB, 1);
    if (idb < HMAX) pk = (u32)(idb + 1);
    if (dg > 100) {
      int ida = atomicAdd(hcA, 1);
      if (ida < HMAX) pk |= (u32)(ida + 1) << 16;
    }
  }
  idAB[v] = pk;
}

// ---------------- hfill: PRNG-bucket heavy edges ----------------
__global__ __launch_bounds__(256) void k_hfill(const int* __restrict__ srcCnt, const u32* __restrict__ srcRec,
                                               const u32* __restrict__ idAB,
                                               int* __restrict__ bcA, u64* __restrict__ bukA,
                                               int* __restrict__ bcB, u64* __restrict__ bukB,
                                               u32 kaA, u32 kbA, u32 kaB, u32 kbB) {
  int bk = blockIdx.x >> 3;
  int part = blockIdx.x & (SPLIT - 1);
  int total = min(srcCnt[bk], SB_CAP);
  int lo = total * part / SPLIT;
  int hi = total * (part + 1) / SPLIT;
  const u32* R = srcRec + (size_t)bk * SB_CAP;
  int base = bk * 512;
  for (int i = lo + threadIdx.x; i < hi; i += 256) {
    u32 r = R[i];
    u32 pk = idAB[base + (int)(r >> 21)];
    if (pk) {
      u32 e = r & 0x1FFFFFu;
      int idb = (int)(pk & 0xFFFFu) - 1;
      if (idb >= 0) {
        u32 w0, w1; tf2x32(kaB, kbB, 0u, e, w0, w1);
        int slot = atomicAdd(&bcB[idb], 1);
        if (slot < MAXD) bukB[(size_t)idb * MAXD + slot] = ((u64)((w0 ^ w1) >> 9) << 32) | e;
      }
      int ida = (int)(pk >> 16) - 1;
      if (ida >= 0) {
        u32 w0, w1; tf2x32(kaA, kbA, 0u, e, w0, w1);
        int slot = atomicAdd(&bcA[ida], 1);
        if (slot < MAXD) bukA[(size_t)ida * MAXD + slot] = ((u64)((w0 ^ w1) >> 9) << 32) | e;
      }
    }
  }
}

// ---------------- rank (both phases in one launch): drop rank >= S ----------------
__global__ __launch_bounds__(256) void k_rank2(const int* __restrict__ hcA, const int* __restrict__ bcA,
                                               const u64* __restrict__ bukA,
                                               const int* __restrict__ hcB, const int* __restrict__ bcB,
                                               const u64* __restrict__ bukB,
                                               unsigned char* __restrict__ mask) {
  bool isA = blockIdx.x < (HMAX / 4);
  int bx = isA ? blockIdx.x : blockIdx.x - HMAX / 4;
  const int* hcount = isA ? hcA : hcB;
  const int* bcount = isA ? bcA : bcB;
  const u64* bucket = isA ? bukA : bukB;
  int S = isA ? 100 : 50;
  int bit = isA ? 1 : 2;
  int wid = (bx * 256 + (int)threadIdx.x) >> 6;
  int lane = threadIdx.x & 63;
  int hc = hcount[0]; if (hc > HMAX) hc = HMAX;
  if (wid >= hc) return;
  int d = bcount[wid]; if (d > MAXD) d = MAXD;
  const u64* B = bucket + (size_t)wid * MAXD;
  for (int i = lane; i < d; i += 64) {
    u64 ki = B[i];
    int rank = 0;
    for (int j = 0; j < d; ++j) rank += (B[j] < ki) ? 1 : 0;
    if (rank >= S) {
      u32 e = (u32)ki;
      mask[e] = (unsigned char)(mask[e] & ~bit);
    }
  }
}

// ---------------- phase 1: binned scatter of edge records ----------------
// record = src(0:15) | dstlow(16:24) | m1(25) | m2(26)
#define P1CHUNK 8192
__global__ __launch_bounds__(256) void k_phase1(const int* __restrict__ ei,
                                                const unsigned char* __restrict__ mask,
                                                int* __restrict__ bucketCur, u32* __restrict__ records, int E) {
  __shared__ u32 lc[128];
  __shared__ u32 lbase[128];
  int t = threadIdx.x;
  if (t < 128) lc[t] = 0;
  __syncthreads();
  int lo = blockIdx.x * P1CHUNK;
  int hi = min(lo + P1CHUNK, E);
  for (int i = lo + t; i < hi; i += 256) {
    int d = ei[E + i];
    atomicAdd(&lc[d >> 9], 1u);
  }
  __syncthreads();
  if (t < 128) {
    u32 c = lc[t];
    if (c) lbase[t] = (u32)atomicAdd(&bucketCur[t], (int)c);
    lc[t] = 0;
  }
  __syncthreads();
  for (int i = lo + t; i < hi; i += 256) {
    int s = ei[i];
    int d = ei[E + i];
    unsigned char m = mask[i];
    int bk = d >> 9;
    u32 slot = lbase[bk] + atomicAdd(&lc[bk], 1u);
    records[slot] = (u32)s | ((u32)(d & 511) << 16) | ((u32)(m & 3u) << 25);
  }
}

// ---------------- phase 2: per-bucket counting sort -> entries/dptr/dinv ----------------
__global__ __launch_bounds__(256) void k_phase2(const int* __restrict__ bucketBase,
                                                const u32* __restrict__ records,
                                                u32* __restrict__ entries, int* __restrict__ dptr,
                                                float* __restrict__ dinv1, float* __restrict__ dinv2, int N) {
  int b = blockIdx.x;
  int lo = bucketBase[b], hi = bucketBase[b + 1];
  __shared__ u32 cnt[512];
  __shared__ u32 ws4[4];
  int t = threadIdx.x;
  cnt[t] = 0; cnt[t + 256] = 0;
  __syncthreads();
  for (int i = lo + t; i < hi; i += 256) {
    u32 r = records[i];
    u32 dl = (r >> 16) & 511u;
    u32 add = 1u + (((r >> 25) & 1u) << 10) + (((r >> 26) & 1u) << 20);
    atomicAdd(&cnt[dl], add);
  }
  __syncthreads();
  u32 c0 = cnt[2 * t], c1 = cnt[2 * t + 1];
  u32 n0 = c0 & 1023u, n1 = c1 & 1023u;
  u32 pair = n0 + n1;
  int lane = t & 63, w = t >> 6;
  u32 incl = pair;
  for (int off = 1; off < 64; off <<= 1) {
    u32 nbv = (u32)__shfl_up((int)incl, off, 64);
    if (lane >= off) incl += nbv;
  }
  if (lane == 63) ws4[w] = incl;
  __syncthreads();
  if (t == 0) { u32 s = 0; for (int k = 0; k < 4; ++k) { u32 x = ws4[k]; ws4[k] = s; s += x; } }
  __syncthreads();
  u32 excl = incl - pair + ws4[w];
  int v0 = b * 512 + 2 * t;
  if (v0 < N) {
    dptr[v0] = lo + (int)excl;
    dinv1[v0] = 1.0f / sqrtf((float)(((c0 >> 10) & 1023u) + 1u));
    dinv2[v0] = 1.0f / sqrtf((float)(((c0 >> 20) & 1023u) + 1u));
  }
  if (v0 + 1 < N) {
    dptr[v0 + 1] = lo + (int)(excl + n0);
    dinv1[v0 + 1] = 1.0f / sqrtf((float)(((c1 >> 10) & 1023u) + 1u));
    dinv2[v0 + 1] = 1.0f / sqrtf((float)(((c1 >> 20) & 1023u) + 1u));
  }
  __syncthreads();
  cnt[2 * t] = excl;
  cnt[2 * t + 1] = excl + n0;
  __syncthreads();
  for (int i = lo + t; i < hi; i += 256) {
    u32 r = records[i];
    u32 dl = (r >> 16) & 511u;
    u32 slot = atomicAdd(&cnt[dl], 1u);
    entries[lo + slot] = (r & 0xFFFFu) | ((r & (1u << 25)) ? (1u << 30) : 0u)
                                       | ((r & (1u << 26)) ? (1u << 31) : 0u);
  }
}

// ---------------- gemm1: h1 = bf16(x) @ bf16(W1), MFMA 16x16x32, K-split staging ----------------
#define G1S 136   // LDS row stride (128 + 8 pad) -> 2-way bank alias only (free)
__global__ __launch_bounds__(256) void k_gemm1(const float* __restrict__ x, const u16* __restrict__ W1t,
                                               u16* __restrict__ h1b, int N) {
  __shared__ u16 xs[64 * G1S];
  __shared__ u16 ws[64 * G1S];
  int t = threadIdx.x;
  int wv = t >> 6, lane = t & 63;
  int qd = lane >> 4, md = lane & 15;
  int m0 = blockIdx.x * 64;
  f4 acc[4] = {};
  for (int ks = 0; ks < 256; ks += 128) {
    __syncthreads();
#pragma unroll
    for (int i = 0; i < 8; ++i) {               // stage x[m0..+63][ks..+127] -> bf16 LDS
      int f = t + 256 * i;                       // 2048 float4s
      int r = f >> 5, c4 = f & 31;
      int grow = m0 + r; if (grow >= N) grow = N - 1;
      float4 v = ((const float4*)x)[(size_t)grow * 64 + (ks >> 2) + c4];
      u32 p0 = (u32)f2bf(v.x) | ((u32)f2bf(v.y) << 16);
      u32 p1 = (u32)f2bf(v.z) | ((u32)f2bf(v.w) << 16);
      *((uint2*)(xs + r * G1S + c4 * 4)) = make_uint2(p0, p1);
    }
#pragma unroll
    for (int i = 0; i < 4; ++i) {               // stage W1t[0..63][ks..+127]
      int cc = t + 256 * i;                      // 1024 chunks of 8 u16
      int n = cc >> 4, kc = (cc & 15) * 8;
      *((uint4*)(ws + n * G1S + kc)) = *((const uint4*)(W1t + n * 256 + ks + kc));
    }
    __syncthreads();
#pragma unroll
    for (int kk = 0; kk < 128; kk += 32) {
      bh8 af = *((const bh8*)(xs + (16 * wv + md) * G1S + kk + qd * 8));
#pragma unroll
      for (int nt = 0; nt < 4; ++nt) {
        bh8 bf = *((const bh8*)(ws + (nt * 16 + md) * G1S + kk + qd * 8));
        acc[nt] = mfma16(af, bf, acc[nt]);
      }
    }
  }
#pragma unroll
  for (int nt = 0; nt < 4; ++nt)
#pragma unroll
    for (int r = 0; r < 4; ++r) {
      int row = m0 + 16 * wv + qd * 4 + r;
      if (row < N) h1b[(size_t)row * 64 + nt * 16 + md] = f2bf(acc[nt][r]);
    }
}

// ---------------- conv1: aggregate h1 + bias + relu + L2 normalize -> bf16 hnb ----------------
// wave per dst; quarter-wave: 16 lanes x uint2(8B) = 128B row, 4 src rows in flight
__global__ __launch_bounds__(256) void k_conv1n(const int* __restrict__ ptr, const u32* __restrict__ entries,
                                                const float* __restrict__ dinv1, const uint2* __restrict__ h1v,
                                                const float* __restrict__ b1, uint2* __restrict__ hnb, int N) {
  int wid = (blockIdx.x * 256 + threadIdx.x) >> 6;
  if (wid >= N) return;
  int lane = threadIdx.x & 63;
  int lq = lane & 15, qw = lane >> 4;
  int beg = ptr[wid], end = ptr[wid + 1];
  float a0 = 0.f, a1 = 0.f, a2 = 0.f, a3 = 0.f;
  for (int cb = beg; cb < end; cb += 64) {
    int idx = cb + lane;
    float wgt = 0.f; int s = 0;
    if (idx < end) {
      u32 e = entries[idx];
      s = (int)(e & 0xFFFFu);
      if (e & (1u << 30)) wgt = dinv1[s];
    }
    int nq = (min(64, end - cb) + 3) >> 2;
    for (int i = 0; i < nq; ++i) {
      int j = 4 * i + qw;
      float w = __shfl(wgt, j, 64);
      int sj  = __shfl(s, j, 64);
      uint2 uv = h1v[(size_t)sj * 16 + lq];
      a0 = fmaf(w, __uint_as_float(uv.x << 16), a0);
      a1 = fmaf(w, __uint_as_float(uv.x & 0xFFFF0000u), a1);
      a2 = fmaf(w, __uint_as_float(uv.y << 16), a2);
      a3 = fmaf(w, __uint_as_float(uv.y & 0xFFFF0000u), a3);
    }
  }
  a0 += __shfl_xor(a0, 16, 64); a0 += __shfl_xor(a0, 32, 64);
  a1 += __shfl_xor(a1, 16, 64); a1 += __shfl_xor(a1, 32, 64);
  a2 += __shfl_xor(a2, 16, 64); a2 += __shfl_xor(a2, 32, 64);
  a3 += __shfl_xor(a3, 16, 64); a3 += __shfl_xor(a3, 32, 64);
  float dv = dinv1[wid];
  uint2 uo = h1v[(size_t)wid * 16 + lq];
  a0 = fmaf(dv, __uint_as_float(uo.x << 16), a0);
  a1 = fmaf(dv, __uint_as_float(uo.x & 0xFFFF0000u), a1);
  a2 = fmaf(dv, __uint_as_float(uo.y << 16), a2);
  a3 = fmaf(dv, __uint_as_float(uo.y & 0xFFFF0000u), a3);
  float4 bb = ((const float4*)b1)[lq];
  float o0 = fmaxf(fmaf(dv, a0, bb.x), 0.f);
  float o1 = fmaxf(fmaf(dv, a1, bb.y), 0.f);
  float o2 = fmaxf(fmaf(dv, a2, bb.z), 0.f);
  float o3 = fmaxf(fmaf(dv, a3, bb.w), 0.f);
  float ss = fmaf(o0, o0, fmaf(o1, o1, fmaf(o2, o2, o3 * o3)));
#pragma unroll
  for (int off = 8; off > 0; off >>= 1) ss += __shfl_xor(ss, off, 16);
  float sc = 1.f / fmaxf(sqrtf(ss), 1e-12f);
  if (lane < 16) {
    u32 p0 = (u32)f2bf(o0 * sc) | ((u32)f2bf(o1 * sc) << 16);
    u32 p1 = (u32)f2bf(o2 * sc) | ((u32)f2bf(o3 * sc) << 16);
    hnb[(size_t)wid * 16 + lq] = make_uint2(p0, p1);
  }
}

// ---------------- agg2: aggregate hnb with dinv2 -> bf16 agg2b (gemm moved after) ----------------
__global__ __launch_bounds__(256) void k_agg2(const int* __restrict__ ptr, const u32* __restrict__ entries,
                                              const float* __restrict__ dinv2, const uint2* __restrict__ hnv,
                                              uint2* __restrict__ agg2b, int N) {
  int wid = (blockIdx.x * 256 + threadIdx.x) >> 6;
  if (wid >= N) return;
  int lane = threadIdx.x & 63;
  int lq = lane & 15, qw = lane >> 4;
  int beg = ptr[wid], end = ptr[wid + 1];
  float a0 = 0.f, a1 = 0.f, a2 = 0.f, a3 = 0.f;
  for (int cb = beg; cb < end; cb += 64) {
    int idx = cb + lane;
    float wgt = 0.f; int s = 0;
    if (idx < end) {
      u32 e = entries[idx];
      s = (int)(e & 0xFFFFu);
      if (e & (1u << 31)) wgt = dinv2[s];
    }
    int nq = (min(64, end - cb) + 3) >> 2;
    for (int i = 0; i < nq; ++i) {
      int j = 4 * i + qw;
      float w = __shfl(wgt, j, 64);
      int sj  = __shfl(s, j, 64);
      uint2 uv = hnv[(size_t)sj * 16 + lq];
      a0 = fmaf(w, __uint_as_float(uv.x << 16), a0);
      a1 = fmaf(w, __uint_as_float(uv.x & 0xFFFF0000u), a1);
      a2 = fmaf(w, __uint_as_float(uv.y << 16), a2);
      a3 = fmaf(w, __uint_as_float(uv.y & 0xFFFF0000u), a3);
    }
  }
  a0 += __shfl_xor(a0, 16, 64); a0 += __shfl_xor(a0, 32, 64);
  a1 += __shfl_xor(a1, 16, 64); a1 += __shfl_xor(a1, 32, 64);
  a2 += __shfl_xor(a2, 16, 64); a2 += __shfl_xor(a2, 32, 64);
  a3 += __shfl_xor(a3, 16, 64); a3 += __shfl_xor(a3, 32, 64);
  float dv = dinv2[wid];
  uint2 uo = hnv[(size_t)wid * 16 + lq];
  a0 = fmaf(dv, __uint_as_float(uo.x << 16), a0);
  a1 = fmaf(dv, __uint_as_float(uo.x & 0xFFFF0000u), a1);
  a2 = fmaf(dv, __uint_as_float(uo.y << 16), a2);
  a3 = fmaf(dv, __uint_as_float(uo.y & 0xFFFF0000u), a3);
  if (lane < 16) {
    u32 p0 = (u32)f2bf(dv * a0) | ((u32)f2bf(dv * a1) << 16);
    u32 p1 = (u32)f2bf(dv * a2) | ((u32)f2bf(dv * a3) << 16);
    agg2b[(size_t)wid * 16 + lq] = make_uint2(p0, p1);
  }
}

// ---------------- gemm2f: out = agg2b @ W2 + b2 (MFMA, fused bias, fp32 out) ----------------
#define G2S 72
__global__ __launch_bounds__(256) void k_gemm2f(const u16* __restrict__ aggb, const u16* __restrict__ W2t,
                                                const float* __restrict__ b2, float* __restrict__ out, int N) {
  __shared__ u16 hs[64 * G2S];
  __shared__ u16 ws[128 * G2S];
  int t = threadIdx.x;
  int wv = t >> 6, lane = t & 63;
  int qd = lane >> 4, md = lane & 15;
  int m0 = blockIdx.x * 64;
#pragma unroll
  for (int i = 0; i < 2; ++i) {                 // stage aggb: 64 rows x 64 u16 = 512 uint4
    int cc = t + 256 * i;
    int r = cc >> 3, kc = (cc & 7) * 8;
    int grow = m0 + r; if (grow >= N) grow = N - 1;
    *((uint4*)(hs + r * G2S + kc)) = *((const uint4*)(aggb + (size_t)grow * 64 + kc));
  }
#pragma unroll
  for (int i = 0; i < 4; ++i) {                 // stage W2t (128x64 u16)
    int cc = t + 256 * i;
    int n = cc >> 3, kc = (cc & 7) * 8;
    *((uint4*)(ws + n * G2S + kc)) = *((const uint4*)(W2t + n * 64 + kc));
  }
  __syncthreads();
  f4 acc[8] = {};
#pragma unroll
  for (int kk = 0; kk < 64; kk += 32) {
    bh8 af = *((const bh8*)(hs + (16 * wv + md) * G2S + kk + qd * 8));
#pragma unroll
    for (int nt = 0; nt < 8; ++nt) {
      bh8 bf = *((const bh8*)(ws + (nt * 16 + md) * G2S + kk + qd * 8));
      acc[nt] = mfma16(af, bf, acc[nt]);
    }
  }
#pragma unroll
  for (int nt = 0; nt < 8; ++nt) {
    float bv = b2[nt * 16 + md];
#pragma unroll
    for (int r = 0; r < 4; ++r) {
      int row = m0 + 16 * wv + qd * 4 + r;
      if (row < N) out[(size_t)row * 128 + nt * 16 + md] = acc[nt][r] + bv;
    }
  }
}

// ---------------- launch ----------------
extern "C" void kernel_launch(void* const* d_in, const int* in_sizes, int n_in,
                              void* d_out, int out_size, void* d_ws, size_t ws_size,
                              hipStream_t stream) {
  const float* x  = (const float*)d_in[0];
  const int*   ei = (const int*)d_in[1];
  const float* W1 = (const float*)d_in[2];
  const float* b1 = (const float*)d_in[3];
  const float* W2 = (const float*)d_in[4];
  const float* b2 = (const float*)d_in[5];
  const int N = in_sizes[0] / 256;
  const int E = in_sizes[1] / 2;
  const int nb = (N + 511) >> 9;   // buckets (98 for N=50000; code assumes <=128)

  u32 sk1a, sk1b, sk2a, sk2b;
  tf2x32(0u, 42u, 0u, 0u, sk1a, sk1b);
  tf2x32(0u, 42u, 0u, 1u, sk2a, sk2b);

  char* p = (char*)d_ws;
  auto alloc = [&](size_t bytes) { char* r = p; p += (bytes + 255) & ~(size_t)255; return r; };
  // --- zero-init group (contiguous) ---
  int* dstCnt      = (int*)alloc(128 * 4);
  int* srcCnt      = (int*)alloc(128 * 4);
  int* hcbA        = (int*)alloc((size_t)(1 + HMAX) * 4);
  int* hcbB        = (int*)alloc((size_t)(1 + HMAX) * 4);
  int* outdegB     = (int*)alloc((size_t)nb * 512 * 4);
  char* zero_end = p;
  // --- rest ---
  unsigned char* mask = (unsigned char*)alloc((size_t)E);
  u32* idAB     = (u32*)alloc((size_t)nb * 512 * 4);
  u16* h1b      = (u16*)alloc((size_t)N * 64 * 2);
  u16* hnb      = (u16*)alloc((size_t)N * 64 * 2);
  u16* agg2b    = (u16*)alloc((size_t)N * 64 * 2);
  float* dinv1  = (float*)alloc((size_t)N * 4);
  float* dinv2  = (float*)alloc((size_t)N * 4);
  int* dptr     = (int*)alloc((size_t)(N + 1) * 4);
  int* bucketBase = (int*)alloc(129 * 4);
  int* bucketCur  = (int*)alloc(128 * 4);
  u32* records  = (u32*)alloc((size_t)E * 4);
  u32* entries  = (u32*)alloc((size_t)E * 4);
  u32* srcRec   = (u32*)alloc((size_t)nb * SB_CAP * 4);
  u64* bukA     = (u64*)alloc((size_t)HMAX * MAXD * 8);
  u64* bukB     = (u64*)alloc((size_t)HMAX * MAXD * 8);
  u16* W1t      = (u16*)alloc(256 * 64 * 2);
  u16* W2t      = (u16*)alloc(64 * 128 * 2);

  int* hcA = hcbA; int* bcA = hcbA + 1;
  int* hcB = hcbB; int* bcB = hcbB + 1;

  hipMemsetAsync(dstCnt, 0x00, (size_t)(zero_end - (char*)dstCnt), stream);
  hipMemsetAsync(mask, 0x03, (size_t)E, stream);

  k_prep<<<4, 256, 0, stream>>>(W1, W2, W1t, W2t);
  k_srcbin<<<(E + SBCHUNK - 1) / SBCHUNK, 256, 0, stream>>>(ei, srcCnt, srcRec, dstCnt, E, nb);
  k_shist<<<nb * SPLIT, 256, 0, stream>>>(srcCnt, srcRec, outdegB);
  k_hdetect<<<(N + 255) / 256, 256, 0, stream>>>(outdegB, idAB, hcA, hcB, dstCnt, bucketBase,
                                                 bucketCur, dptr, nb, N);
  k_hfill<<<nb * SPLIT, 256, 0, stream>>>(srcCnt, srcRec, idAB, bcA, bukA, bcB, bukB,
                                          sk1a, sk1b, sk2a, sk2b);
  k_rank2<<<HMAX / 2, 256, 0, stream>>>(hcA, bcA, bukA, hcB, bcB, bukB, mask);
  k_phase1<<<(E + P1CHUNK - 1) / P1CHUNK, 256, 0, stream>>>(ei, mask, bucketCur, records, E);
  k_phase2<<<nb, 256, 0, stream>>>(bucketBase, records, entries, dptr, dinv1, dinv2, N);

  k_gemm1<<<(N + 63) / 64, 256, 0, stream>>>(x, W1t, h1b, N);
  k_conv1n<<<(N * 64 + 255) / 256, 256, 0, stream>>>(dptr, entries, dinv1, (const uint2*)h1b, b1,
                                                     (uint2*)hnb, N);
  k_agg2<<<(N * 64 + 255) / 256, 256, 0, stream>>>(dptr, entries, dinv2, (const uint2*)hnb,
                                                   (uint2*)agg2b, N);
  k_gemm2f<<<(N + 63) / 64, 256, 0, stream>>>(agg2b, W2t, b2, (float*)d_out, N);
}

// Round 7
// 313.317 us; speedup vs baseline: 2.6638x; 1.0643x over previous
//
#include <hip/hip_runtime.h>

typedef unsigned int u32;
typedef unsigned short u16;
typedef unsigned long long u64;
typedef __attribute__((ext_vector_type(8))) short bh8;   // 8 bf16 (4 VGPRs) MFMA frag
typedef __attribute__((ext_vector_type(4))) float f4;    // 4 fp32 acc

#define HMAX 1024   // max heavy (deg>S) nodes tracked; expected ~65
#define MAXD 128    // max out-degree bucketed; expected max ~58
#define SB_CAP 24576  // src-bin capacity: mean 16384, sigma ~127 -> +64 sigma
#define SBCHUNK 2048
#define SPLIT 8     // blocks per src bucket in shist/hfill

__device__ inline f4 mfma16(bh8 a, bh8 b, f4 c) {
  return __builtin_amdgcn_mfma_f32_16x16x32_bf16(a, b, c, 0, 0, 0);
}

// ---------------- threefry2x32 (exact JAX cipher) ----------------
__host__ __device__ inline void tf2x32(u32 k0, u32 k1, u32 x0, u32 x1, u32& o0, u32& o1) {
  u32 ks2 = k0 ^ k1 ^ 0x1BD11BDAu;
#define ROTL32(x,d) (((x)<<(d))|((x)>>(32-(d))))
#define TFR(r) { x0 += x1; x1 = ROTL32(x1,(r)); x1 ^= x0; }
  x0 += k0; x1 += k1;
  TFR(13) TFR(15) TFR(26) TFR(6)
  x0 += k1; x1 += ks2 + 1u;
  TFR(17) TFR(29) TFR(16) TFR(24)
  x0 += ks2; x1 += k0 + 2u;
  TFR(13) TFR(15) TFR(26) TFR(6)
  x0 += k0; x1 += k1 + 3u;
  TFR(17) TFR(29) TFR(16) TFR(24)
  x0 += k1; x1 += ks2 + 4u;
  TFR(13) TFR(15) TFR(26) TFR(6)
  x0 += ks2; x1 += k0 + 5u;
  o0 = x0; o1 = x1;
#undef TFR
#undef ROTL32
}

__device__ inline u16 f2bf(float f) {      // round-to-nearest-even (finite inputs)
  u32 u = __float_as_uint(f);
  return (u16)((u + 0x7FFFu + ((u >> 16) & 1u)) >> 16);
}
__device__ inline float bflo(u32 u) { return __uint_as_float(u << 16); }
__device__ inline float bfhi(u32 u) { return __uint_as_float(u & 0xFFFF0000u); }

// ---------------- weight pre-transpose to bf16 n-major ----------------
__global__ __launch_bounds__(256) void k_prep(const float* __restrict__ W1, const float* __restrict__ W2,
                                              u16* __restrict__ W1t, u16* __restrict__ W2t) {
  int t = blockIdx.x * 256 + threadIdx.x;   // grid 4 x 256
  for (int e = t; e < 256 * 64; e += 1024) {
    int n = e & 63, k = e >> 6;
    W1t[n * 256 + k] = f2bf(W1[k * 64 + n]);
  }
  for (int e = t; e < 64 * 128; e += 1024) {
    int n = e & 127, k = e >> 7;
    W2t[n * 64 + k] = f2bf(W2[k * 128 + n]);
  }
}

// ---------------- src-binned record scatter + dst-bucket histogram ----------------
// src record = srclow9 (21:29) | edgeid (0:20)
__global__ __launch_bounds__(256) void k_srcbin(const int* __restrict__ ei,
                                                int* __restrict__ srcCnt, u32* __restrict__ srcRec,
                                                int* __restrict__ dstCnt, int E, int nb) {
  __shared__ u32 lsrc[128], ldst[128], lbase[128];
  int t = threadIdx.x;
  if (t < 128) { lsrc[t] = 0; ldst[t] = 0; }
  __syncthreads();
  int lo = blockIdx.x * SBCHUNK;
  int hi = min(lo + SBCHUNK, E);
  int sv[SBCHUNK / 256];
  int ci = 0;
  for (int i = lo + t; i < hi; i += 256) {
    int s = ei[i];
    int d = ei[E + i];
    sv[ci++] = s;
    atomicAdd(&lsrc[s >> 9], 1u);
    atomicAdd(&ldst[d >> 9], 1u);
  }
  __syncthreads();
  if (t < 128) {
    u32 c = lsrc[t];
    if (c) lbase[t] = (u32)atomicAdd(&srcCnt[t], (int)c);
    lsrc[t] = 0;
    if (ldst[t]) atomicAdd(&dstCnt[t], (int)ldst[t]);
  }
  __syncthreads();
  ci = 0;
  for (int i = lo + t; i < hi; i += 256) {
    int s = sv[ci++];
    int bk = s >> 9;
    u32 slot = lbase[bk] + atomicAdd(&lsrc[bk], 1u);
    if (slot < SB_CAP)
      srcRec[(size_t)bk * SB_CAP + slot] = ((u32)(s & 511) << 21) | (u32)i;
  }
}

// ---------------- shist: partial LDS histograms -> global outdegB ----------------
__global__ __launch_bounds__(256) void k_shist(const int* __restrict__ srcCnt, const u32* __restrict__ srcRec,
                                               int* __restrict__ outdegB) {
  int bk = blockIdx.x >> 3;          // / SPLIT
  int part = blockIdx.x & (SPLIT - 1);
  int total = min(srcCnt[bk], SB_CAP);
  int lo = total * part / SPLIT;
  int hi = total * (part + 1) / SPLIT;
  __shared__ u32 cnt[512];
  int t = threadIdx.x;
  cnt[t] = 0; cnt[t + 256] = 0;
  __syncthreads();
  const u32* R = srcRec + (size_t)bk * SB_CAP;
  for (int i = lo + t; i < hi; i += 256) atomicAdd(&cnt[R[i] >> 21], 1u);
  __syncthreads();
  int base = bk * 512;
  for (int v = t; v < 512; v += 256) {
    u32 c = cnt[v];
    if (c) atomicAdd(&outdegB[base + v], (int)c);
  }
}

// ---------------- hdetect: heavy-id assignment (+ folded dst-bucket scan) ----------------
__global__ __launch_bounds__(256) void k_hdetect(const int* __restrict__ outdegB, u32* __restrict__ idAB,
                                                 int* __restrict__ hcA, int* __restrict__ hcB,
                                                 const int* __restrict__ dstCnt, int* __restrict__ bucketBase,
                                                 int* __restrict__ bucketCur, int* __restrict__ dptr,
                                                 int nb, int N) {
  if (blockIdx.x == 0 && threadIdx.x == 0) {
    int s = 0;
    for (int i = 0; i < nb; ++i) { bucketBase[i] = s; bucketCur[i] = s; s += dstCnt[i]; }
    bucketBase[nb] = s;
    dptr[N] = s;   // == E
  }
  int v = blockIdx.x * 256 + threadIdx.x;
  if (v >= N) return;
  int dg = outdegB[v];
  u32 pk = 0;
  if (dg > 50) {
    int idb = atomicAdd(hcB, 1);
    if (idb < HMAX) pk = (u32)(idb + 1);
    if (dg > 100) {
      int ida = atomicAdd(hcA, 1);
      if (ida < HMAX) pk |= (u32)(ida + 1) << 16;
    }
  }
  idAB[v] = pk;
}

// ---------------- hfill: PRNG-bucket heavy edges ----------------
__global__ __launch_bounds__(256) void k_hfill(const int* __restrict__ srcCnt, const u32* __restrict__ srcRec,
                                               const u32* __restrict__ idAB,
                                               int* __restrict__ bcA, u64* __restrict__ bukA,
                                               int* __restrict__ bcB, u64* __restrict__ bukB,
                                               u32 kaA, u32 kbA, u32 kaB, u32 kbB) {
  int bk = blockIdx.x >> 3;
  int part = blockIdx.x & (SPLIT - 1);
  int total = min(srcCnt[bk], SB_CAP);
  int lo = total * part / SPLIT;
  int hi = total * (part + 1) / SPLIT;
  const u32* R = srcRec + (size_t)bk * SB_CAP;
  int base = bk * 512;
  for (int i = lo + threadIdx.x; i < hi; i += 256) {
    u32 r = R[i];
    u32 pk = idAB[base + (int)(r >> 21)];
    if (pk) {
      u32 e = r & 0x1FFFFFu;
      int idb = (int)(pk & 0xFFFFu) - 1;
      if (idb >= 0) {
        u32 w0, w1; tf2x32(kaB, kbB, 0u, e, w0, w1);
        int slot = atomicAdd(&bcB[idb], 1);
        if (slot < MAXD) bukB[(size_t)idb * MAXD + slot] = ((u64)((w0 ^ w1) >> 9) << 32) | e;
      }
      int ida = (int)(pk >> 16) - 1;
      if (ida >= 0) {
        u32 w0, w1; tf2x32(kaA, kbA, 0u, e, w0, w1);
        int slot = atomicAdd(&bcA[ida], 1);
        if (slot < MAXD) bukA[(size_t)ida * MAXD + slot] = ((u64)((w0 ^ w1) >> 9) << 32) | e;
      }
    }
  }
}

// ---------------- rank (both phases in one launch): drop rank >= S ----------------
__global__ __launch_bounds__(256) void k_rank2(const int* __restrict__ hcA, const int* __restrict__ bcA,
                                               const u64* __restrict__ bukA,
                                               const int* __restrict__ hcB, const int* __restrict__ bcB,
                                               const u64* __restrict__ bukB,
                                               unsigned char* __restrict__ mask) {
  bool isA = blockIdx.x < (HMAX / 4);
  int bx = isA ? blockIdx.x : blockIdx.x - HMAX / 4;
  const int* hcount = isA ? hcA : hcB;
  const int* bcount = isA ? bcA : bcB;
  const u64* bucket = isA ? bukA : bukB;
  int S = isA ? 100 : 50;
  int bit = isA ? 1 : 2;
  int wid = (bx * 256 + (int)threadIdx.x) >> 6;
  int lane = threadIdx.x & 63;
  int hc = hcount[0]; if (hc > HMAX) hc = HMAX;
  if (wid >= hc) return;
  int d = bcount[wid]; if (d > MAXD) d = MAXD;
  const u64* B = bucket + (size_t)wid * MAXD;
  for (int i = lane; i < d; i += 64) {
    u64 ki = B[i];
    int rank = 0;
    for (int j = 0; j < d; ++j) rank += (B[j] < ki) ? 1 : 0;
    if (rank >= S) {
      u32 e = (u32)ki;
      mask[e] = (unsigned char)(mask[e] & ~bit);
    }
  }
}

// ---------------- phase 1: binned scatter of edge records ----------------
// record = src(0:15) | dstlow(16:24) | m1(25) | m2(26)
#define P1CHUNK 8192
__global__ __launch_bounds__(256) void k_phase1(const int* __restrict__ ei,
                                                const unsigned char* __restrict__ mask,
                                                int* __restrict__ bucketCur, u32* __restrict__ records, int E) {
  __shared__ u32 lc[128];
  __shared__ u32 lbase[128];
  int t = threadIdx.x;
  if (t < 128) lc[t] = 0;
  __syncthreads();
  int lo = blockIdx.x * P1CHUNK;
  int hi = min(lo + P1CHUNK, E);
  for (int i = lo + t; i < hi; i += 256) {
    int d = ei[E + i];
    atomicAdd(&lc[d >> 9], 1u);
  }
  __syncthreads();
  if (t < 128) {
    u32 c = lc[t];
    if (c) lbase[t] = (u32)atomicAdd(&bucketCur[t], (int)c);
    lc[t] = 0;
  }
  __syncthreads();
  for (int i = lo + t; i < hi; i += 256) {
    int s = ei[i];
    int d = ei[E + i];
    unsigned char m = mask[i];
    int bk = d >> 9;
    u32 slot = lbase[bk] + atomicAdd(&lc[bk], 1u);
    records[slot] = (u32)s | ((u32)(d & 511) << 16) | ((u32)(m & 3u) << 25);
  }
}

// ---------------- phase 2: per-bucket counting sort -> entries/dptr/dinv ----------------
__global__ __launch_bounds__(256) void k_phase2(const int* __restrict__ bucketBase,
                                                const u32* __restrict__ records,
                                                u32* __restrict__ entries, int* __restrict__ dptr,
                                                float* __restrict__ dinv1, float* __restrict__ dinv2, int N) {
  int b = blockIdx.x;
  int lo = bucketBase[b], hi = bucketBase[b + 1];
  __shared__ u32 cnt[512];
  __shared__ u32 ws4[4];
  int t = threadIdx.x;
  cnt[t] = 0; cnt[t + 256] = 0;
  __syncthreads();
  for (int i = lo + t; i < hi; i += 256) {
    u32 r = records[i];
    u32 dl = (r >> 16) & 511u;
    u32 add = 1u + (((r >> 25) & 1u) << 10) + (((r >> 26) & 1u) << 20);
    atomicAdd(&cnt[dl], add);
  }
  __syncthreads();
  u32 c0 = cnt[2 * t], c1 = cnt[2 * t + 1];
  u32 n0 = c0 & 1023u, n1 = c1 & 1023u;
  u32 pair = n0 + n1;
  int lane = t & 63, w = t >> 6;
  u32 incl = pair;
  for (int off = 1; off < 64; off <<= 1) {
    u32 nbv = (u32)__shfl_up((int)incl, off, 64);
    if (lane >= off) incl += nbv;
  }
  if (lane == 63) ws4[w] = incl;
  __syncthreads();
  if (t == 0) { u32 s = 0; for (int k = 0; k < 4; ++k) { u32 x = ws4[k]; ws4[k] = s; s += x; } }
  __syncthreads();
  u32 excl = incl - pair + ws4[w];
  int v0 = b * 512 + 2 * t;
  if (v0 < N) {
    dptr[v0] = lo + (int)excl;
    dinv1[v0] = 1.0f / sqrtf((float)(((c0 >> 10) & 1023u) + 1u));
    dinv2[v0] = 1.0f / sqrtf((float)(((c0 >> 20) & 1023u) + 1u));
  }
  if (v0 + 1 < N) {
    dptr[v0 + 1] = lo + (int)(excl + n0);
    dinv1[v0 + 1] = 1.0f / sqrtf((float)(((c1 >> 10) & 1023u) + 1u));
    dinv2[v0 + 1] = 1.0f / sqrtf((float)(((c1 >> 20) & 1023u) + 1u));
  }
  __syncthreads();
  cnt[2 * t] = excl;
  cnt[2 * t + 1] = excl + n0;
  __syncthreads();
  for (int i = lo + t; i < hi; i += 256) {
    u32 r = records[i];
    u32 dl = (r >> 16) & 511u;
    u32 slot = atomicAdd(&cnt[dl], 1u);
    entries[lo + slot] = (r & 0xFFFFu) | ((r & (1u << 25)) ? (1u << 30) : 0u)
                                       | ((r & (1u << 26)) ? (1u << 31) : 0u);
  }
}

// ---------------- gemm1: h1 = bf16(x) @ bf16(W1), MFMA 16x16x32, K-split staging ----------------
#define G1S 136   // LDS row stride (128 + 8 pad) -> 2-way bank alias only (free)
__global__ __launch_bounds__(256) void k_gemm1(const float* __restrict__ x, const u16* __restrict__ W1t,
                                               u16* __restrict__ h1b, int N) {
  __shared__ u16 xs[64 * G1S];
  __shared__ u16 ws[64 * G1S];
  int t = threadIdx.x;
  int wv = t >> 6, lane = t & 63;
  int qd = lane >> 4, md = lane & 15;
  int m0 = blockIdx.x * 64;
  f4 acc[4] = {};
  for (int ks = 0; ks < 256; ks += 128) {
    __syncthreads();
#pragma unroll
    for (int i = 0; i < 8; ++i) {               // stage x[m0..+63][ks..+127] -> bf16 LDS
      int f = t + 256 * i;                       // 2048 float4s
      int r = f >> 5, c4 = f & 31;
      int grow = m0 + r; if (grow >= N) grow = N - 1;
      float4 v = ((const float4*)x)[(size_t)grow * 64 + (ks >> 2) + c4];
      u32 p0 = (u32)f2bf(v.x) | ((u32)f2bf(v.y) << 16);
      u32 p1 = (u32)f2bf(v.z) | ((u32)f2bf(v.w) << 16);
      *((uint2*)(xs + r * G1S + c4 * 4)) = make_uint2(p0, p1);
    }
#pragma unroll
    for (int i = 0; i < 4; ++i) {               // stage W1t[0..63][ks..+127]
      int cc = t + 256 * i;                      // 1024 chunks of 8 u16
      int n = cc >> 4, kc = (cc & 15) * 8;
      *((uint4*)(ws + n * G1S + kc)) = *((const uint4*)(W1t + n * 256 + ks + kc));
    }
    __syncthreads();
#pragma unroll
    for (int kk = 0; kk < 128; kk += 32) {
      bh8 af = *((const bh8*)(xs + (16 * wv + md) * G1S + kk + qd * 8));
#pragma unroll
      for (int nt = 0; nt < 4; ++nt) {
        bh8 bf = *((const bh8*)(ws + (nt * 16 + md) * G1S + kk + qd * 8));
        acc[nt] = mfma16(af, bf, acc[nt]);
      }
    }
  }
#pragma unroll
  for (int nt = 0; nt < 4; ++nt)
#pragma unroll
    for (int r = 0; r < 4; ++r) {
      int row = m0 + 16 * wv + qd * 4 + r;
      if (row < N) h1b[(size_t)row * 64 + nt * 16 + md] = f2bf(acc[nt][r]);
    }
}

// ---------------- conv1: aggregate h1 + bias + relu + L2 normalize -> bf16 hnb ----------------
// wave per dst; eighth-wave: 8 lanes x uint4(16B) = 128B row, 8 rows in flight + 1-deep pipeline
__global__ __launch_bounds__(256) void k_conv1n(const int* __restrict__ ptr, const u32* __restrict__ entries,
                                                const float* __restrict__ dinv1, const uint4* __restrict__ h1q,
                                                const float* __restrict__ b1, uint4* __restrict__ hnbq, int N) {
  int wid = (blockIdx.x * 256 + threadIdx.x) >> 6;
  if (wid >= N) return;
  int lane = threadIdx.x & 63;
  int lo8 = lane & 7, grp = lane >> 3;
  int beg = ptr[wid], end = ptr[wid + 1];
  float a0 = 0.f, a1 = 0.f, a2 = 0.f, a3 = 0.f, a4 = 0.f, a5 = 0.f, a6 = 0.f, a7 = 0.f;
  for (int cb = beg; cb < end; cb += 64) {
    int idx = cb + lane;
    float wgt = 0.f; int s = 0;
    if (idx < end) {
      u32 e = entries[idx];
      s = (int)(e & 0xFFFFu);
      if (e & (1u << 30)) wgt = dinv1[s];
    }
    int nq = (min(64, end - cb) + 7) >> 3;
    int j = grp;
    float w = __shfl(wgt, j, 64);
    int sj = __shfl(s, j, 64);
    uint4 uv = h1q[(size_t)sj * 8 + lo8];
    for (int i = 1; i < nq; ++i) {
      int j2 = j + 8;
      float w2 = __shfl(wgt, j2, 64);
      int s2 = __shfl(s, j2, 64);
      uint4 uv2 = h1q[(size_t)s2 * 8 + lo8];
      a0 = fmaf(w, bflo(uv.x), a0); a1 = fmaf(w, bfhi(uv.x), a1);
      a2 = fmaf(w, bflo(uv.y), a2); a3 = fmaf(w, bfhi(uv.y), a3);
      a4 = fmaf(w, bflo(uv.z), a4); a5 = fmaf(w, bfhi(uv.z), a5);
      a6 = fmaf(w, bflo(uv.w), a6); a7 = fmaf(w, bfhi(uv.w), a7);
      w = w2; uv = uv2; j = j2;
    }
    a0 = fmaf(w, bflo(uv.x), a0); a1 = fmaf(w, bfhi(uv.x), a1);
    a2 = fmaf(w, bflo(uv.y), a2); a3 = fmaf(w, bfhi(uv.y), a3);
    a4 = fmaf(w, bflo(uv.z), a4); a5 = fmaf(w, bfhi(uv.z), a5);
    a6 = fmaf(w, bflo(uv.w), a6); a7 = fmaf(w, bfhi(uv.w), a7);
  }
#pragma unroll
  for (int off = 8; off < 64; off <<= 1) {
    a0 += __shfl_xor(a0, off, 64); a1 += __shfl_xor(a1, off, 64);
    a2 += __shfl_xor(a2, off, 64); a3 += __shfl_xor(a3, off, 64);
    a4 += __shfl_xor(a4, off, 64); a5 += __shfl_xor(a5, off, 64);
    a6 += __shfl_xor(a6, off, 64); a7 += __shfl_xor(a7, off, 64);
  }
  float dv = dinv1[wid];
  uint4 uo = h1q[(size_t)wid * 8 + lo8];
  a0 = fmaf(dv, bflo(uo.x), a0); a1 = fmaf(dv, bfhi(uo.x), a1);
  a2 = fmaf(dv, bflo(uo.y), a2); a3 = fmaf(dv, bfhi(uo.y), a3);
  a4 = fmaf(dv, bflo(uo.z), a4); a5 = fmaf(dv, bfhi(uo.z), a5);
  a6 = fmaf(dv, bflo(uo.w), a6); a7 = fmaf(dv, bfhi(uo.w), a7);
  float4 bbA = ((const float4*)b1)[lo8 * 2];
  float4 bbB = ((const float4*)b1)[lo8 * 2 + 1];
  float o0 = fmaxf(fmaf(dv, a0, bbA.x), 0.f);
  float o1 = fmaxf(fmaf(dv, a1, bbA.y), 0.f);
  float o2 = fmaxf(fmaf(dv, a2, bbA.z), 0.f);
  float o3 = fmaxf(fmaf(dv, a3, bbA.w), 0.f);
  float o4 = fmaxf(fmaf(dv, a4, bbB.x), 0.f);
  float o5 = fmaxf(fmaf(dv, a5, bbB.y), 0.f);
  float o6 = fmaxf(fmaf(dv, a6, bbB.z), 0.f);
  float o7 = fmaxf(fmaf(dv, a7, bbB.w), 0.f);
  float ss = fmaf(o0, o0, fmaf(o1, o1, fmaf(o2, o2, o3 * o3)))
           + fmaf(o4, o4, fmaf(o5, o5, fmaf(o6, o6, o7 * o7)));
#pragma unroll
  for (int off = 1; off < 8; off <<= 1) ss += __shfl_xor(ss, off, 8);
  float sc = 1.f / fmaxf(sqrtf(ss), 1e-12f);
  if (lane < 8) {
    uint4 pv;
    pv.x = (u32)f2bf(o0 * sc) | ((u32)f2bf(o1 * sc) << 16);
    pv.y = (u32)f2bf(o2 * sc) | ((u32)f2bf(o3 * sc) << 16);
    pv.z = (u32)f2bf(o4 * sc) | ((u32)f2bf(o5 * sc) << 16);
    pv.w = (u32)f2bf(o6 * sc) | ((u32)f2bf(o7 * sc) << 16);
    hnbq[(size_t)wid * 8 + lo8] = pv;
  }
}

// ---------------- agg2: aggregate hnb with dinv2 -> bf16 agg2b (gemm moved after) ----------------
__global__ __launch_bounds__(256) void k_agg2(const int* __restrict__ ptr, const u32* __restrict__ entries,
                                              const float* __restrict__ dinv2, const uint4* __restrict__ hnq,
                                              uint4* __restrict__ agg2q, int N) {
  int wid = (blockIdx.x * 256 + threadIdx.x) >> 6;
  if (wid >= N) return;
  int lane = threadIdx.x & 63;
  int lo8 = lane & 7, grp = lane >> 3;
  int beg = ptr[wid], end = ptr[wid + 1];
  float a0 = 0.f, a1 = 0.f, a2 = 0.f, a3 = 0.f, a4 = 0.f, a5 = 0.f, a6 = 0.f, a7 = 0.f;
  for (int cb = beg; cb < end; cb += 64) {
    int idx = cb + lane;
    float wgt = 0.f; int s = 0;
    if (idx < end) {
      u32 e = entries[idx];
      s = (int)(e & 0xFFFFu);
      if (e & (1u << 31)) wgt = dinv2[s];
    }
    int nq = (min(64, end - cb) + 7) >> 3;
    int j = grp;
    float w = __shfl(wgt, j, 64);
    int sj = __shfl(s, j, 64);
    uint4 uv = hnq[(size_t)sj * 8 + lo8];
    for (int i = 1; i < nq; ++i) {
      int j2 = j + 8;
      float w2 = __shfl(wgt, j2, 64);
      int s2 = __shfl(s, j2, 64);
      uint4 uv2 = hnq[(size_t)s2 * 8 + lo8];
      a0 = fmaf(w, bflo(uv.x), a0); a1 = fmaf(w, bfhi(uv.x), a1);
      a2 = fmaf(w, bflo(uv.y), a2); a3 = fmaf(w, bfhi(uv.y), a3);
      a4 = fmaf(w, bflo(uv.z), a4); a5 = fmaf(w, bfhi(uv.z), a5);
      a6 = fmaf(w, bflo(uv.w), a6); a7 = fmaf(w, bfhi(uv.w), a7);
      w = w2; uv = uv2; j = j2;
    }
    a0 = fmaf(w, bflo(uv.x), a0); a1 = fmaf(w, bfhi(uv.x), a1);
    a2 = fmaf(w, bflo(uv.y), a2); a3 = fmaf(w, bfhi(uv.y), a3);
    a4 = fmaf(w, bflo(uv.z), a4); a5 = fmaf(w, bfhi(uv.z), a5);
    a6 = fmaf(w, bflo(uv.w), a6); a7 = fmaf(w, bfhi(uv.w), a7);
  }
#pragma unroll
  for (int off = 8; off < 64; off <<= 1) {
    a0 += __shfl_xor(a0, off, 64); a1 += __shfl_xor(a1, off, 64);
    a2 += __shfl_xor(a2, off, 64); a3 += __shfl_xor(a3, off, 64);
    a4 += __shfl_xor(a4, off, 64); a5 += __shfl_xor(a5, off, 64);
    a6 += __shfl_xor(a6, off, 64); a7 += __shfl_xor(a7, off, 64);
  }
  float dv = dinv2[wid];
  uint4 uo = hnq[(size_t)wid * 8 + lo8];
  a0 = fmaf(dv, bflo(uo.x), a0); a1 = fmaf(dv, bfhi(uo.x), a1);
  a2 = fmaf(dv, bflo(uo.y), a2); a3 = fmaf(dv, bfhi(uo.y), a3);
  a4 = fmaf(dv, bflo(uo.z), a4); a5 = fmaf(dv, bfhi(uo.z), a5);
  a6 = fmaf(dv, bflo(uo.w), a6); a7 = fmaf(dv, bfhi(uo.w), a7);
  if (lane < 8) {
    uint4 pv;
    pv.x = (u32)f2bf(dv * a0) | ((u32)f2bf(dv * a1) << 16);
    pv.y = (u32)f2bf(dv * a2) | ((u32)f2bf(dv * a3) << 16);
    pv.z = (u32)f2bf(dv * a4) | ((u32)f2bf(dv * a5) << 16);
    pv.w = (u32)f2bf(dv * a6) | ((u32)f2bf(dv * a7) << 16);
    agg2q[(size_t)wid * 8 + lo8] = pv;
  }
}

// ---------------- gemm2f: out = agg2b @ W2 + b2 (MFMA, fused bias, fp32 out) ----------------
#define G2S 72
__global__ __launch_bounds__(256) void k_gemm2f(const u16* __restrict__ aggb, const u16* __restrict__ W2t,
                                                const float* __restrict__ b2, float* __restrict__ out, int N) {
  __shared__ u16 hs[64 * G2S];
  __shared__ u16 ws[128 * G2S];
  int t = threadIdx.x;
  int wv = t >> 6, lane = t & 63;
  int qd = lane >> 4, md = lane & 15;
  int m0 = blockIdx.x * 64;
#pragma unroll
  for (int i = 0; i < 2; ++i) {                 // stage aggb: 64 rows x 64 u16 = 512 uint4
    int cc = t + 256 * i;
    int r = cc >> 3, kc = (cc & 7) * 8;
    int grow = m0 + r; if (grow >= N) grow = N - 1;
    *((uint4*)(hs + r * G2S + kc)) = *((const uint4*)(aggb + (size_t)grow * 64 + kc));
  }
#pragma unroll
  for (int i = 0; i < 4; ++i) {                 // stage W2t (128x64 u16)
    int cc = t + 256 * i;
    int n = cc >> 3, kc = (cc & 7) * 8;
    *((uint4*)(ws + n * G2S + kc)) = *((const uint4*)(W2t + n * 64 + kc));
  }
  __syncthreads();
  f4 acc[8] = {};
#pragma unroll
  for (int kk = 0; kk < 64; kk += 32) {
    bh8 af = *((const bh8*)(hs + (16 * wv + md) * G2S + kk + qd * 8));
#pragma unroll
    for (int nt = 0; nt < 8; ++nt) {
      bh8 bf = *((const bh8*)(ws + (nt * 16 + md) * G2S + kk + qd * 8));
      acc[nt] = mfma16(af, bf, acc[nt]);
    }
  }
#pragma unroll
  for (int nt = 0; nt < 8; ++nt) {
    float bv = b2[nt * 16 + md];
#pragma unroll
    for (int r = 0; r < 4; ++r) {
      int row = m0 + 16 * wv + qd * 4 + r;
      if (row < N) out[(size_t)row * 128 + nt * 16 + md] = acc[nt][r] + bv;
    }
  }
}

// ---------------- launch ----------------
extern "C" void kernel_launch(void* const* d_in, const int* in_sizes, int n_in,
                              void* d_out, int out_size, void* d_ws, size_t ws_size,
                              hipStream_t stream) {
  const float* x  = (const float*)d_in[0];
  const int*   ei = (const int*)d_in[1];
  const float* W1 = (const float*)d_in[2];
  const float* b1 = (const float*)d_in[3];
  const float* W2 = (const float*)d_in[4];
  const float* b2 = (const float*)d_in[5];
  const int N = in_sizes[0] / 256;
  const int E = in_sizes[1] / 2;
  const int nb = (N + 511) >> 9;   // buckets (98 for N=50000; code assumes <=128)

  u32 sk1a, sk1b, sk2a, sk2b;
  tf2x32(0u, 42u, 0u, 0u, sk1a, sk1b);
  tf2x32(0u, 42u, 0u, 1u, sk2a, sk2b);

  char* p = (char*)d_ws;
  auto alloc = [&](size_t bytes) { char* r = p; p += (bytes + 255) & ~(size_t)255; return r; };
  // --- zero-init group (contiguous) ---
  int* dstCnt      = (int*)alloc(128 * 4);
  int* srcCnt      = (int*)alloc(128 * 4);
  int* hcbA        = (int*)alloc((size_t)(1 + HMAX) * 4);
  int* hcbB        = (int*)alloc((size_t)(1 + HMAX) * 4);
  int* outdegB     = (int*)alloc((size_t)nb * 512 * 4);
  char* zero_end = p;
  // --- rest ---
  unsigned char* mask = (unsigned char*)alloc((size_t)E);
  u32* idAB     = (u32*)alloc((size_t)nb * 512 * 4);
  u16* h1b      = (u16*)alloc((size_t)N * 64 * 2);
  u16* hnb      = (u16*)alloc((size_t)N * 64 * 2);
  u16* agg2b    = (u16*)alloc((size_t)N * 64 * 2);
  float* dinv1  = (float*)alloc((size_t)N * 4);
  float* dinv2  = (float*)alloc((size_t)N * 4);
  int* dptr     = (int*)alloc((size_t)(N + 1) * 4);
  int* bucketBase = (int*)alloc(129 * 4);
  int* bucketCur  = (int*)alloc(128 * 4);
  u32* records  = (u32*)alloc((size_t)E * 4);
  u32* entries  = (u32*)alloc((size_t)E * 4);
  u32* srcRec   = (u32*)alloc((size_t)nb * SB_CAP * 4);
  u64* bukA     = (u64*)alloc((size_t)HMAX * MAXD * 8);
  u64* bukB     = (u64*)alloc((size_t)HMAX * MAXD * 8);
  u16* W1t      = (u16*)alloc(256 * 64 * 2);
  u16* W2t      = (u16*)alloc(64 * 128 * 2);

  int* hcA = hcbA; int* bcA = hcbA + 1;
  int* hcB = hcbB; int* bcB = hcbB + 1;

  hipMemsetAsync(dstCnt, 0x00, (size_t)(zero_end - (char*)dstCnt), stream);
  hipMemsetAsync(mask, 0x03, (size_t)E, stream);

  k_prep<<<4, 256, 0, stream>>>(W1, W2, W1t, W2t);
  k_srcbin<<<(E + SBCHUNK - 1) / SBCHUNK, 256, 0, stream>>>(ei, srcCnt, srcRec, dstCnt, E, nb);
  k_shist<<<nb * SPLIT, 256, 0, stream>>>(srcCnt, srcRec, outdegB);
  k_hdetect<<<(N + 255) / 256, 256, 0, stream>>>(outdegB, idAB, hcA, hcB, dstCnt, bucketBase,
                                                 bucketCur, dptr, nb, N);
  k_hfill<<<nb * SPLIT, 256, 0, stream>>>(srcCnt, srcRec, idAB, bcA, bukA, bcB, bukB,
                                          sk1a, sk1b, sk2a, sk2b);
  k_rank2<<<HMAX / 2, 256, 0, stream>>>(hcA, bcA, bukA, hcB, bcB, bukB, mask);
  k_phase1<<<(E + P1CHUNK - 1) / P1CHUNK, 256, 0, stream>>>(ei, mask, bucketCur, records, E);
  k_phase2<<<nb, 256, 0, stream>>>(bucketBase, records, entries, dptr, dinv1, dinv2, N);

  k_gemm1<<<(N + 63) / 64, 256, 0, stream>>>(x, W1t, h1b, N);
  k_conv1n<<<(N * 64 + 255) / 256, 256, 0, stream>>>(dptr, entries, dinv1, (const uint4*)h1b, b1,
                                                     (uint4*)hnb, N);
  k_agg2<<<(N * 64 + 255) / 256, 256, 0, stream>>>(dptr, entries, dinv2, (const uint4*)hnb,
                                                   (uint4*)agg2b, N);
  k_gemm2f<<<(N + 63) / 64, 256, 0, stream>>>(agg2b, W2t, b2, (float*)d_out, N);
}